// Round 2
// baseline (4894.651 us; speedup 1.0000x reference)
//
#include <hip/hip_runtime.h>

// ============================================================================
// TransformerChoiceNet forward. Round 2: compact workspace (224.5 MiB; round-1
// crash attributed to 437 MB ws overflow), bf16 layer-boundary tensors,
// fp32 residual streams and fp32 accumulation everywhere.
// B=128 S=512 D=64 H=256 NH=8 HD=32, M=B*S=65536.
// Workspace layout (bytes):
//   P0  fp32[M,256]  64 MiB   (src/enc residual stream)
//   P1  fp32[M,256]  64 MiB   (trg/dec residual stream)
//   H1  bf16[M,256]  32 MiB
//   H2  bf16[M,256]  32 MiB
//   H0  bf16[M,256]  32 MiB   (aliases xs[M,64]+xt[M,64] fp32, dead post-emb)
//   valid fp32[M]   256 KiB
//   logits fp32[M]  256 KiB
// ============================================================================

#define Bb  128
#define Ss  512
#define Dd  64
#define Hh  256
#define NHh 8
#define HDd 32
#define Mm  (Bb*Ss)
#define SCP 516

typedef unsigned short bf16_t;

__device__ __forceinline__ float bf2f(bf16_t h){
  union { unsigned int u; float f; } v; v.u = ((unsigned int)h)<<16; return v.f;
}
__device__ __forceinline__ bf16_t f2bf(float f){
  union { float f; unsigned int u; } v; v.f = f;
  unsigned int r = (v.u + 0x7fffu + ((v.u>>16)&1u)) >> 16;   // RNE
  return (bf16_t)r;
}

__device__ __forceinline__ float gelu_f(float x){
  float u = 0.7978845608028654f*(x + 0.044715f*x*x*x);
  return 0.5f*x*(1.0f + tanhf(u));
}

// ---------------- LN0 (two gains) + valid mask --------------------------------
__global__ __launch_bounds__(256) void k_ln0(const float* __restrict__ src,
    const float* __restrict__ gs, const float* __restrict__ bs,
    const float* __restrict__ gt, const float* __restrict__ bt,
    float* __restrict__ xs, float* __restrict__ xt, float* __restrict__ valid)
{
  int row  = blockIdx.x*4 + (threadIdx.x>>6);
  int lane = threadIdx.x & 63;
  float x = src[(size_t)row*Dd + lane];
  float s = x;
  #pragma unroll
  for (int o=32;o>0;o>>=1) s += __shfl_xor(s,o);
  float mean = s*(1.0f/64.0f);
  float d = x - mean;
  float ss = d*d;
  #pragma unroll
  for (int o=32;o>0;o>>=1) ss += __shfl_xor(ss,o);
  float r = rsqrtf(ss*(1.0f/64.0f) + 1e-5f);
  float xn = d*r;
  xs[(size_t)row*Dd+lane] = xn*gs[lane] + bs[lane];
  xt[(size_t)row*Dd+lane] = xn*gt[lane] + bt[lane];
  if (lane==0) valid[row] = (s != 0.0f) ? 1.0f : 0.0f;
}

// ---------------- GEMM: C[M,N] = epi(A[M,K] @ W[K,N] + bias) ------------------
// 128x64 tile, BK=16, 256 threads, 8x4 per-thread register tile.
// TA in {float, bf16_t}; TC in {float, bf16_t}; fp32 accumulate always.
template<typename TA, typename TC, int EPI>   // EPI: 0 none, 1 gelu
__global__ __launch_bounds__(256) void k_gemm(const TA* __restrict__ A,
    const float* __restrict__ W, const float* __restrict__ bias,
    TC* __restrict__ C, int K, int N)
{
  __shared__ float As[16][132];
  __shared__ float Bs[16][64];
  int t  = threadIdx.x;
  int n0 = blockIdx.x*64;
  int m0 = blockIdx.y*128;
  int tx = t & 15;
  int ty = t >> 4;
  float acc[8][4] = {};
  for (int k0=0; k0<K; k0+=16){
    #pragma unroll
    for (int i=0;i<8;i++){
      int idx = t + i*256;
      int m = idx>>4, kk = idx&15;
      TA a = A[(size_t)(m0+m)*K + k0+kk];
      float af;
      if (sizeof(TA)==2) af = bf2f((bf16_t)a); else af = (float)a;
      As[kk][m] = af;
    }
    #pragma unroll
    for (int i=0;i<4;i++){
      int idx = t + i*256;
      int kk = idx>>6, n = idx&63;
      Bs[kk][n] = W[(size_t)(k0+kk)*N + n0+n];
    }
    __syncthreads();
    #pragma unroll
    for (int kk=0;kk<16;kk++){
      float4 a0 = *(const float4*)&As[kk][ty*8];
      float4 a1 = *(const float4*)&As[kk][ty*8+4];
      float4 b4 = *(const float4*)&Bs[kk][tx*4];
      float am[8] = {a0.x,a0.y,a0.z,a0.w,a1.x,a1.y,a1.z,a1.w};
      float bn[4] = {b4.x,b4.y,b4.z,b4.w};
      #pragma unroll
      for (int i=0;i<8;i++)
        #pragma unroll
        for (int j=0;j<4;j++)
          acc[i][j] = fmaf(am[i], bn[j], acc[i][j]);
    }
    __syncthreads();
  }
  float4 b4 = *(const float4*)&bias[n0 + tx*4];
  #pragma unroll
  for (int i=0;i<8;i++){
    float c0 = acc[i][0] + b4.x;
    float c1 = acc[i][1] + b4.y;
    float c2 = acc[i][2] + b4.z;
    float c3 = acc[i][3] + b4.w;
    if (EPI==1){ c0=gelu_f(c0); c1=gelu_f(c1); c2=gelu_f(c2); c3=gelu_f(c3); }
    size_t off = (size_t)(m0 + ty*8 + i)*N + n0 + tx*4;
    if (sizeof(TC)==2){
      ushort4 h; h.x=f2bf(c0); h.y=f2bf(c1); h.z=f2bf(c2); h.w=f2bf(c3);
      *(ushort4*)&C[off] = h;
    } else {
      float4 c; c.x=c0; c.y=c1; c.z=c2; c.w=c3;
      *(float4*)&C[off] = c;
    }
  }
}

// ---------------- residual add + LayerNorm: O = LN(A + B), B is bf16 ----------
__global__ __launch_bounds__(256) void k_add_ln(const float* __restrict__ A,
    const bf16_t* __restrict__ Bv, const float* __restrict__ g,
    const float* __restrict__ bb, float* __restrict__ O)
{
  int row  = blockIdx.x*4 + (threadIdx.x>>6);
  int lane = threadIdx.x & 63;
  float4 va = ((const float4*)(A + (size_t)row*Hh))[lane];
  ushort4 hb = ((const ushort4*)(Bv + (size_t)row*Hh))[lane];
  float4 v = {va.x+bf2f(hb.x), va.y+bf2f(hb.y), va.z+bf2f(hb.z), va.w+bf2f(hb.w)};
  float s = v.x+v.y+v.z+v.w;
  #pragma unroll
  for (int o=32;o>0;o>>=1) s += __shfl_xor(s,o);
  float mean = s*(1.0f/256.0f);
  float dx=v.x-mean, dy=v.y-mean, dz=v.z-mean, dw=v.w-mean;
  float ss = dx*dx+dy*dy+dz*dz+dw*dw;
  #pragma unroll
  for (int o=32;o>0;o>>=1) ss += __shfl_xor(ss,o);
  float r = rsqrtf(ss*(1.0f/256.0f) + 1e-5f);
  float4 g4  = ((const float4*)g)[lane];
  float4 bb4 = ((const float4*)bb)[lane];
  float4 o4  = { dx*r*g4.x+bb4.x, dy*r*g4.y+bb4.y, dz*r*g4.z+bb4.z, dw*r*g4.w+bb4.w };
  ((float4*)(O + (size_t)row*Hh))[lane] = o4;
}

// ---------------- attention: one block per (b, h, 16 q-rows), bf16 I/O --------
// Q/K/V/AO layout: [B*S, 256] bf16, head h at cols h*32..h*32+31.
// AO may alias Qm: each block reads its Q tile into LDS before writing the
// same addresses, and blocks touch disjoint regions.
__global__ __launch_bounds__(256) void k_attn(const bf16_t* __restrict__ Qm,
    const bf16_t* __restrict__ Km, const bf16_t* __restrict__ Vm,
    const float* __restrict__ valid, bf16_t* __restrict__ AO)
{
  __shared__ float Sc[8448];      // 16 x SCP scores; reused as 256 x 33 partials
  __shared__ float Ks[64][36];    // K (then V) chunk
  __shared__ float Qs[16][32];
  __shared__ float rs[16];
  int t   = threadIdx.x;
  int bid = blockIdx.x;
  int qt = bid & 31;
  int h  = (bid >> 5) & 7;
  int b  = bid >> 8;
  int q0 = qt * 16;
  const float scale = 0.17677669529663687f;   // 1/sqrt(32)

  for (int idx=t; idx<16*32; idx+=256){
    int qi = idx>>5, d = idx&31;
    Qs[qi][d] = bf2f(Qm[((size_t)(b*Ss + q0+qi)<<8) + (h<<5) + d]) * scale;
  }
  __syncthreads();

  // ---- scores: each thread owns 2 q rows (in regs), 32 k's per 64-chunk ----
  int qi0 = (t&7)*2;
  int ks  = t>>3;
  float qa[32], qb[32];
  #pragma unroll
  for (int d=0; d<32; d+=4){
    float4 x0 = *(const float4*)&Qs[qi0][d];
    qa[d]=x0.x; qa[d+1]=x0.y; qa[d+2]=x0.z; qa[d+3]=x0.w;
    float4 x1 = *(const float4*)&Qs[qi0+1][d];
    qb[d]=x1.x; qb[d+1]=x1.y; qb[d+2]=x1.z; qb[d+3]=x1.w;
  }

  for (int kt=0; kt<Ss; kt+=64){
    __syncthreads();
    {                                     // stage 64x32 bf16 chunk: uint4 = 8 vals
      int r = t>>2, c8 = (t&3)<<3;
      uint4 u = *(const uint4*)(Km + ((size_t)(b*Ss + kt + r)<<8) + (h<<5) + c8);
      Ks[r][c8+0]=bf2f(u.x&0xffff); Ks[r][c8+1]=bf2f(u.x>>16);
      Ks[r][c8+2]=bf2f(u.y&0xffff); Ks[r][c8+3]=bf2f(u.y>>16);
      Ks[r][c8+4]=bf2f(u.z&0xffff); Ks[r][c8+5]=bf2f(u.z>>16);
      Ks[r][c8+6]=bf2f(u.w&0xffff); Ks[r][c8+7]=bf2f(u.w>>16);
    }
    __syncthreads();
    #pragma unroll
    for (int j=0;j<2;j++){
      int k = ks + 32*j;
      float s0=0.f, s1=0.f;
      #pragma unroll
      for (int d=0; d<32; d+=4){
        float4 kv = *(const float4*)&Ks[k][d];
        s0 = fmaf(qa[d],kv.x,s0); s0 = fmaf(qa[d+1],kv.y,s0);
        s0 = fmaf(qa[d+2],kv.z,s0); s0 = fmaf(qa[d+3],kv.w,s0);
        s1 = fmaf(qb[d],kv.x,s1); s1 = fmaf(qb[d+1],kv.y,s1);
        s1 = fmaf(qb[d+2],kv.z,s1); s1 = fmaf(qb[d+3],kv.w,s1);
      }
      float vld = valid[b*Ss + kt + k];
      if (vld == 0.0f){ s0 = -1e10f; s1 = -1e10f; }
      Sc[ qi0   *SCP + kt + k] = s0;
      Sc[(qi0+1)*SCP + kt + k] = s1;
    }
  }
  __syncthreads();

  // ---- softmax over 512, 16 lanes per row ----
  {
    int row = t>>4, l16 = t&15;
    float mx = -3.0e38f;
    for (int k=l16; k<Ss; k+=16) mx = fmaxf(mx, Sc[row*SCP+k]);
    #pragma unroll
    for (int o=8;o>0;o>>=1) mx = fmaxf(mx, __shfl_xor(mx,o,16));
    float sm = 0.f;
    for (int k=l16; k<Ss; k+=16){
      float p = __expf(Sc[row*SCP+k] - mx);
      Sc[row*SCP+k] = p;
      sm += p;
    }
    #pragma unroll
    for (int o=8;o>0;o>>=1) sm += __shfl_xor(sm,o,16);
    if (l16==0) rs[row] = sm;
  }

  // ---- PV: thread = (qg: 8 q-rows, d4: 4 dims, ksl: k-slice of 4/chunk) ----
  int qg  = t & 1;
  int d4  = ((t>>1)&7) << 2;
  int ksl = t >> 4;
  float4 po[8];
  #pragma unroll
  for (int qq=0;qq<8;qq++) po[qq] = make_float4(0.f,0.f,0.f,0.f);

  for (int kt=0; kt<Ss; kt+=64){
    __syncthreads();                        // first iter also fences softmax
    {
      int r = t>>2, c8 = (t&3)<<3;
      uint4 u = *(const uint4*)(Vm + ((size_t)(b*Ss + kt + r)<<8) + (h<<5) + c8);
      Ks[r][c8+0]=bf2f(u.x&0xffff); Ks[r][c8+1]=bf2f(u.x>>16);
      Ks[r][c8+2]=bf2f(u.y&0xffff); Ks[r][c8+3]=bf2f(u.y>>16);
      Ks[r][c8+4]=bf2f(u.z&0xffff); Ks[r][c8+5]=bf2f(u.z>>16);
      Ks[r][c8+6]=bf2f(u.w&0xffff); Ks[r][c8+7]=bf2f(u.w>>16);
    }
    __syncthreads();
    #pragma unroll
    for (int kk=0;kk<4;kk++){
      int k = (ksl<<2) + kk;
      float4 vv = *(const float4*)&Ks[k][d4];
      #pragma unroll
      for (int qq=0;qq<8;qq++){
        float p = Sc[(qg*8+qq)*SCP + kt + k];
        po[qq].x = fmaf(p,vv.x,po[qq].x);
        po[qq].y = fmaf(p,vv.y,po[qq].y);
        po[qq].z = fmaf(p,vv.z,po[qq].z);
        po[qq].w = fmaf(p,vv.w,po[qq].w);
      }
    }
  }
  __syncthreads();
  #pragma unroll
  for (int qq=0;qq<8;qq++){                 // partials -> Sc as [256][33]
    int base = t*33 + (qq<<2);
    Sc[base+0]=po[qq].x; Sc[base+1]=po[qq].y; Sc[base+2]=po[qq].z; Sc[base+3]=po[qq].w;
  }
  __syncthreads();
  #pragma unroll
  for (int rep=0; rep<2; rep++){            // reduce 16 k-slices, write AO
    int o  = t + rep*256;
    int qi = o>>5, d = o&31;
    int qg2 = qi>>3, qq2 = qi&7;
    int v  = (qq2<<2) + (d&3);
    int bt = ((d>>2)<<1) | qg2;
    float sum = 0.f;
    #pragma unroll
    for (int k2=0;k2<16;k2++) sum += Sc[(bt + (k2<<4))*33 + v];
    AO[((size_t)(b*Ss + q0 + qi)<<8) + (h<<5) + d] = f2bf(sum / rs[qi]);
  }
}

// ---------------- out projection: logits[m] = T[m,:] . outW + outb ------------
__global__ __launch_bounds__(256) void k_logits(const float* __restrict__ T,
    const float* __restrict__ oW, const float* __restrict__ ob, float* __restrict__ L)
{
  int row  = blockIdx.x*4 + (threadIdx.x>>6);
  int lane = threadIdx.x & 63;
  float4 tv = ((const float4*)(T + (size_t)row*Hh))[lane];
  float4 wv = ((const float4*)oW)[lane];
  float s = tv.x*wv.x + tv.y*wv.y + tv.z*wv.z + tv.w*wv.w;
  #pragma unroll
  for (int o=32;o>0;o>>=1) s += __shfl_xor(s,o);
  if (lane==0) L[row] = s + ob[0];
}

// ---------------- final: p = exp(logits)*valid, normalize per batch -----------
__global__ __launch_bounds__(256) void k_final(const float* __restrict__ L,
    const float* __restrict__ valid, float* __restrict__ out)
{
  __shared__ float wsum[4];
  int b = blockIdx.x, t = threadIdx.x;
  float e0 = __expf(L[b*Ss + t      ]) * valid[b*Ss + t      ];
  float e1 = __expf(L[b*Ss + 256 + t]) * valid[b*Ss + 256 + t];
  float s = e0 + e1;
  #pragma unroll
  for (int o=32;o>0;o>>=1) s += __shfl_xor(s,o);
  if ((t&63)==0) wsum[t>>6] = s;
  __syncthreads();
  float tot = wsum[0]+wsum[1]+wsum[2]+wsum[3];
  out[b*Ss + t      ] = e0/tot;
  out[b*Ss + 256 + t] = e1/tot;
}

// ============================================================================
extern "C" void kernel_launch(void* const* d_in, const int* in_sizes, int n_in,
                              void* d_out, int out_size, void* d_ws, size_t ws_size,
                              hipStream_t stream)
{
  #define F(i) ((const float*)d_in[(i)])
  // Dict order vs signature order differ for d_ln1 vs d_eq..d_eo block.
  // Dict: idx33=d_eqW (65536 elems); signature: idx33=d_ln1g (256 elems).
  bool sig = (in_sizes[33] == 256);
  const float* d_eqW  = F(sig?35:33); const float* d_eqb  = F(sig?36:34);
  const float* d_ekW  = F(sig?37:35); const float* d_ekb  = F(sig?38:36);
  const float* d_evW  = F(sig?39:37); const float* d_evb  = F(sig?40:38);
  const float* d_eoW  = F(sig?41:39); const float* d_eob  = F(sig?42:40);
  const float* d_ln1g = F(sig?33:41); const float* d_ln1b = F(sig?34:42);

  // ---- workspace carve-up: 224.5 MiB total ----
  char* w = (char*)d_ws;
  float*  P0 = (float*)w;  w += (size_t)Mm*Hh*4;   // 64 MiB
  float*  P1 = (float*)w;  w += (size_t)Mm*Hh*4;   // 64 MiB
  bf16_t* H1 = (bf16_t*)w; w += (size_t)Mm*Hh*2;   // 32 MiB
  bf16_t* H2 = (bf16_t*)w; w += (size_t)Mm*Hh*2;   // 32 MiB
  bf16_t* H0 = (bf16_t*)w;                          // 32 MiB, aliases xs+xt
  float*  xs = (float*)w;  w += (size_t)Mm*Dd*4;   // 16 MiB
  float*  xt = (float*)w;  w += (size_t)Mm*Dd*4;   // 16 MiB
  float*  valid  = (float*)w; w += (size_t)Mm*4;   // 256 KiB
  float*  logits = (float*)w; w += (size_t)Mm*4;   // 256 KiB
  float* out = (float*)d_out;

  dim3 blk(256);
  dim3 gLN(Mm/4);
  dim3 gG(Hh/64, Mm/128);
  dim3 gA(Bb*NHh*(Ss/16));

  k_ln0<<<gLN, blk, 0, stream>>>(F(0), F(1),F(2), F(3),F(4), xs, xt, valid);

  k_gemm<float,float,0><<<gG, blk, 0, stream>>>(xs, F(5), F(6), P0, Dd, Hh);  // embs_src
  k_gemm<float,float,0><<<gG, blk, 0, stream>>>(xt, F(7), F(8), P1, Dd, Hh);  // embs_trg
  // xs/xt dead from here; H0 reuses their region.

  // ---- encoder ----
  k_gemm<float,bf16_t,0><<<gG, blk, 0, stream>>>(P0, F(9),  F(10), H0, Hh, Hh); // Q
  k_gemm<float,bf16_t,0><<<gG, blk, 0, stream>>>(P0, F(11), F(12), H1, Hh, Hh); // K
  k_gemm<float,bf16_t,0><<<gG, blk, 0, stream>>>(P0, F(13), F(14), H2, Hh, Hh); // V
  k_attn<<<gA, blk, 0, stream>>>(H0, H1, H2, valid, H0);                        // AO=H0
  k_gemm<bf16_t,bf16_t,0><<<gG, blk, 0, stream>>>(H0, F(15), F(16), H1, Hh, Hh); // O proj
  k_add_ln<<<gLN, blk, 0, stream>>>(P0, H1, F(17), F(18), P0);                  // x
  k_gemm<float,bf16_t,1><<<gG, blk, 0, stream>>>(P0, F(19), F(20), H0, Hh, Hh); // gelu(f1)
  k_gemm<bf16_t,bf16_t,0><<<gG, blk, 0, stream>>>(H0, F(21), F(22), H2, Hh, Hh); // f2
  k_add_ln<<<gLN, blk, 0, stream>>>(P0, H2, F(23), F(24), P0);                  // enc_src

  // ---- decoder self-attention ----
  k_gemm<float,bf16_t,0><<<gG, blk, 0, stream>>>(P1, F(25), F(26), H0, Hh, Hh); // Q
  k_gemm<float,bf16_t,0><<<gG, blk, 0, stream>>>(P1, F(27), F(28), H1, Hh, Hh); // K
  k_gemm<float,bf16_t,0><<<gG, blk, 0, stream>>>(P1, F(29), F(30), H2, Hh, Hh); // V
  k_attn<<<gA, blk, 0, stream>>>(H0, H1, H2, valid, H0);
  k_gemm<bf16_t,bf16_t,0><<<gG, blk, 0, stream>>>(H0, F(31), F(32), H1, Hh, Hh); // O proj
  k_add_ln<<<gLN, blk, 0, stream>>>(P1, H1, d_ln1g, d_ln1b, P1);                // t

  // ---- decoder cross-attention ----
  k_gemm<float,bf16_t,0><<<gG, blk, 0, stream>>>(P1, d_eqW, d_eqb, H0, Hh, Hh); // Q from t
  k_gemm<float,bf16_t,0><<<gG, blk, 0, stream>>>(P0, d_ekW, d_ekb, H1, Hh, Hh); // K from enc
  k_gemm<float,bf16_t,0><<<gG, blk, 0, stream>>>(P0, d_evW, d_evb, H2, Hh, Hh); // V from enc
  k_attn<<<gA, blk, 0, stream>>>(H0, H1, H2, valid, H0);
  k_gemm<bf16_t,bf16_t,0><<<gG, blk, 0, stream>>>(H0, d_eoW, d_eob, H1, Hh, Hh); // O proj
  k_add_ln<<<gLN, blk, 0, stream>>>(P1, H1, F(43), F(44), P1);                  // t

  // ---- decoder FFN ----
  k_gemm<float,bf16_t,1><<<gG, blk, 0, stream>>>(P1, F(45), F(46), H0, Hh, Hh); // gelu(f1)
  k_gemm<bf16_t,bf16_t,0><<<gG, blk, 0, stream>>>(H0, F(47), F(48), H2, Hh, Hh); // f2
  k_add_ln<<<gLN, blk, 0, stream>>>(P1, H2, F(49), F(50), P1);                  // t

  // ---- output head ----
  k_logits<<<gLN, blk, 0, stream>>>(P1, F(51), F(52), logits);
  k_final<<<dim3(Bb), blk, 0, stream>>>(logits, valid, out);
  #undef F
}

// Round 3
// 2032.894 us; speedup vs baseline: 2.4077x; 2.4077x over previous
//
#include <hip/hip_runtime.h>

// ============================================================================
// TransformerChoiceNet forward. Round 3: MFMA (bf16 16x16x32) GEMM + attention.
// B=128 S=512 D=64 H=256 NH=8 HD=32, M=B*S=65536.
// - k_prep: fp32 weights -> bf16 transposed Wt[n][k] arena (2.1 MB), per call.
// - k_gemm: LDS-free register-tiled MFMA GEMM, wave tile 32x64, block 128x64.
//   A operand fp32 (residual streams, cvt in-flight) or bf16. fp32 accum.
//   Epilogue: none/gelu; out bf16 [M,256], fp32 [M,256], or bf16 VT[b][d][key].
// - k_attn: QK^T via MFMA (K-dim=32=HD, one MFMA/16-key tile), no-max softmax
//   (scores O(5); masked -> exp(-1e10)=0; all-masked rows -> linv=0),
//   P via wave-private LDS round-trip (C-layout -> A-layout), PV via MFMA with
//   V pre-transposed by the V-GEMM epilogue (VT[b][d][key], direct 16B loads).
// Workspace ~226.6 MB (round-2 footprint proved safe at 224.5 MB).
// ============================================================================

#define Bb  128
#define Ss  512
#define Dd  64
#define Hh  256
#define NHh 8
#define Mm  (Bb*Ss)

typedef unsigned short bf16_t;
typedef __attribute__((ext_vector_type(8))) short short8;
typedef __attribute__((ext_vector_type(4))) float f32x4;

__device__ __forceinline__ float bf2f(bf16_t h){
  union { unsigned int u; float f; } v; v.u = ((unsigned int)h)<<16; return v.f;
}
__device__ __forceinline__ bf16_t f2bf(float f){
  union { float f; unsigned int u; } v; v.f = f;
  unsigned int r = (v.u + 0x7fffu + ((v.u>>16)&1u)) >> 16;   // RNE
  return (bf16_t)r;
}
__device__ __forceinline__ short8 ld_bf8(const bf16_t* p){   // 16B global/LDS load
  union { uint4 u; short8 s; } v; v.u = *(const uint4*)p; return v.s;
}
__device__ __forceinline__ short8 cvt_f32x8(const float* p){ // 8 fp32 -> bf16x8
  float4 a = *(const float4*)p; float4 b = *(const float4*)(p+4);
  short8 s;
  s[0]=(short)f2bf(a.x); s[1]=(short)f2bf(a.y); s[2]=(short)f2bf(a.z); s[3]=(short)f2bf(a.w);
  s[4]=(short)f2bf(b.x); s[5]=(short)f2bf(b.y); s[6]=(short)f2bf(b.z); s[7]=(short)f2bf(b.w);
  return s;
}
__device__ __forceinline__ float gelu_f(float x){
  float u = 0.7978845608028654f*(x + 0.044715f*x*x*x);
  return 0.5f*x*(1.0f + tanhf(u));
}

// ---------------- weight prep: fp32 W[k][n] -> bf16 Wt[n][k] ------------------
struct PrepDesc { const float* s; unsigned off; int K; };
struct Prep18  { PrepDesc d[18]; };

__global__ __launch_bounds__(256) void k_prep(Prep18 p, bf16_t* __restrict__ arena)
{
  PrepDesc dd = p.d[blockIdx.y];
  int i = blockIdx.x*256 + threadIdx.x;
  if (i < dd.K*256){
    int k = i>>8, n = i&255;
    arena[dd.off + n*dd.K + k] = f2bf(dd.s[i]);
  }
}

// ---------------- LN0 (two gains) + valid mask; bf16 out ----------------------
__global__ __launch_bounds__(256) void k_ln0(const float* __restrict__ src,
    const float* __restrict__ gs, const float* __restrict__ bs,
    const float* __restrict__ gt, const float* __restrict__ bt,
    bf16_t* __restrict__ xs, bf16_t* __restrict__ xt, float* __restrict__ valid)
{
  int row  = blockIdx.x*4 + (threadIdx.x>>6);
  int lane = threadIdx.x & 63;
  float x = src[(size_t)row*Dd + lane];
  float s = x;
  #pragma unroll
  for (int o=32;o>0;o>>=1) s += __shfl_xor(s,o);
  float mean = s*(1.0f/64.0f);
  float d = x - mean;
  float ss = d*d;
  #pragma unroll
  for (int o=32;o>0;o>>=1) ss += __shfl_xor(ss,o);
  float r = rsqrtf(ss*(1.0f/64.0f) + 1e-5f);
  float xn = d*r;
  xs[(size_t)row*Dd+lane] = f2bf(xn*gs[lane] + bs[lane]);
  xt[(size_t)row*Dd+lane] = f2bf(xn*gt[lane] + bt[lane]);
  if (lane==0) valid[row] = (s != 0.0f) ? 1.0f : 0.0f;
}

// ---------------- MFMA GEMM: C = epi(A[M,K] @ W[K,256] + bias) ----------------
// Wt is bf16 [256][K] (pre-transposed). Wave tile 32m x 64n; block 128m x 64n.
// TAF32: A fp32 (cvt in-flight) vs bf16. OUTM: 0 bf16 [M,256], 1 fp32 [M,256],
// 2 bf16 VT[b][n][s] (attention V layout).
template<int TAF32, int EPI, int OUTM>
__global__ __launch_bounds__(256) void k_gemm(const void* __restrict__ Av,
    const bf16_t* __restrict__ Wt, const float* __restrict__ bias,
    void* __restrict__ Cv, int K)
{
  int t = threadIdx.x, wave = t>>6, lane = t&63, l15 = lane&15, quad = lane>>4;
  int m0 = blockIdx.y*128 + wave*32;
  int n0 = blockIdx.x*64;
  const float*  Af = (const float*)Av;
  const bf16_t* Ab = (const bf16_t*)Av;
  f32x4 z = {0.f,0.f,0.f,0.f};
  f32x4 acc[2][4] = {{z,z,z,z},{z,z,z,z}};

  for (int kc=0; kc<K; kc+=32){
    short8 a[2], b[4];
    #pragma unroll
    for (int mt=0; mt<2; mt++){
      size_t row = (size_t)(m0 + mt*16 + l15);
      if (TAF32) a[mt] = cvt_f32x8(Af + row*K + kc + quad*8);
      else       a[mt] = ld_bf8 (Ab + row*K + kc + quad*8);
    }
    #pragma unroll
    for (int nt=0; nt<4; nt++)
      b[nt] = ld_bf8(Wt + (size_t)(n0 + nt*16 + l15)*K + kc + quad*8);
    #pragma unroll
    for (int mt=0; mt<2; mt++)
      #pragma unroll
      for (int nt=0; nt<4; nt++)
        acc[mt][nt] = __builtin_amdgcn_mfma_f32_16x16x32_bf16(a[mt], b[nt], acc[mt][nt], 0,0,0);
  }

  float bv[4];
  #pragma unroll
  for (int nt=0; nt<4; nt++) bv[nt] = bias[n0 + nt*16 + l15];

  #pragma unroll
  for (int mt=0; mt<2; mt++)
    #pragma unroll
    for (int nt=0; nt<4; nt++)
      #pragma unroll
      for (int r=0; r<4; r++){
        int row = m0 + mt*16 + quad*4 + r;
        int col = n0 + nt*16 + l15;
        float v = acc[mt][nt][r] + bv[nt];
        if (EPI==1) v = gelu_f(v);
        if (OUTM==0)      ((bf16_t*)Cv)[(size_t)row*256 + col] = f2bf(v);
        else if (OUTM==1) ((float*) Cv)[(size_t)row*256 + col] = v;
        else              ((bf16_t*)Cv)[((size_t)(row>>9)*256 + col)*512 + (row&511)] = f2bf(v);
      }
}

// ---------------- residual add + LayerNorm: P = LN(P + Hbf16) -----------------
__global__ __launch_bounds__(256) void k_add_ln(const float* __restrict__ A,
    const bf16_t* __restrict__ Bv, const float* __restrict__ g,
    const float* __restrict__ bb, float* __restrict__ O)
{
  int row  = blockIdx.x*4 + (threadIdx.x>>6);
  int lane = threadIdx.x & 63;
  float4 va = ((const float4*)(A + (size_t)row*Hh))[lane];
  ushort4 hb = ((const ushort4*)(Bv + (size_t)row*Hh))[lane];
  float4 v = {va.x+bf2f(hb.x), va.y+bf2f(hb.y), va.z+bf2f(hb.z), va.w+bf2f(hb.w)};
  float s = v.x+v.y+v.z+v.w;
  #pragma unroll
  for (int o=32;o>0;o>>=1) s += __shfl_xor(s,o);
  float mean = s*(1.0f/256.0f);
  float dx=v.x-mean, dy=v.y-mean, dz=v.z-mean, dw=v.w-mean;
  float ss = dx*dx+dy*dy+dz*dz+dw*dw;
  #pragma unroll
  for (int o=32;o>0;o>>=1) ss += __shfl_xor(ss,o);
  float r = rsqrtf(ss*(1.0f/256.0f) + 1e-5f);
  float4 g4  = ((const float4*)g)[lane];
  float4 bb4 = ((const float4*)bb)[lane];
  float4 o4  = { dx*r*g4.x+bb4.x, dy*r*g4.y+bb4.y, dz*r*g4.z+bb4.z, dw*r*g4.w+bb4.w };
  ((float4*)(O + (size_t)row*Hh))[lane] = o4;
}

// ---------------- MFMA attention ----------------------------------------------
// Block = (b, h, 64 q-rows); wave = 16 q-rows. Q/K [M,256] bf16 (head slice);
// VT [B][256][512] bf16. AO bf16 [M,256] (may alias Qm: block reads only its
// own q-tile/head slice of Q, which is exactly its write region).
__global__ __launch_bounds__(256) void k_attn(const bf16_t* __restrict__ Qm,
    const bf16_t* __restrict__ Km, const bf16_t* __restrict__ VT,
    const float* __restrict__ valid, bf16_t* __restrict__ AO)
{
  __shared__ float  Smask[512];
  __shared__ bf16_t Pbuf[4][16][40];   // wave-private; stride 40 (80B rows)
  int t = threadIdx.x, wave = t>>6, lane = t&63, l15 = lane&15, quad = lane>>4;
  int bid = blockIdx.x;
  int qt = bid & 7, h = (bid>>3) & 7, b = bid>>6;
  int q0 = qt*64;
  const float scale = 0.17677669529663687f;   // 1/sqrt(32)

  Smask[t]     = (valid[b*Ss + t      ] != 0.f) ? 0.f : -1e10f;
  Smask[t+256] = (valid[b*Ss + t + 256] != 0.f) ? 0.f : -1e10f;
  __syncthreads();

  size_t qrow = (size_t)(b*Ss + q0 + wave*16 + l15);
  short8 aQ = ld_bf8(Qm + qrow*256 + h*32 + quad*8);
  const bf16_t* Vbase = VT + ((size_t)b*256 + h*32)*512;

  f32x4 z = {0.f,0.f,0.f,0.f};
  f32x4 O[2] = {z,z};
  float lsum[4] = {0.f,0.f,0.f,0.f};

  for (int kt2=0; kt2<16; kt2++){
    #pragma unroll
    for (int half=0; half<2; half++){
      int ktile = kt2*2 + half;
      short8 bK = ld_bf8(Km + (size_t)(b*Ss + ktile*16 + l15)*256 + h*32 + quad*8);
      f32x4 s = __builtin_amdgcn_mfma_f32_16x16x32_bf16(aQ, bK, z, 0,0,0);
      float mb = Smask[ktile*16 + l15];
      #pragma unroll
      for (int r=0; r<4; r++){
        float p = __expf(s[r]*scale + mb);   // no max-sub: |s*scale| small; masked -> 0
        lsum[r] += p;
        Pbuf[wave][quad*4+r][half*16 + l15] = f2bf(p);
      }
    }
    short8 aP = ld_bf8(&Pbuf[wave][l15][quad*8]);     // C-layout -> A-layout
    #pragma unroll
    for (int nt=0; nt<2; nt++){
      short8 bV = ld_bf8(Vbase + (size_t)(nt*16 + l15)*512 + kt2*32 + quad*8);
      O[nt] = __builtin_amdgcn_mfma_f32_16x16x32_bf16(aP, bV, O[nt], 0,0,0);
    }
  }

  float linv[4];
  #pragma unroll
  for (int r=0; r<4; r++){
    float l = lsum[r];
    l += __shfl_xor(l,1); l += __shfl_xor(l,2);
    l += __shfl_xor(l,4); l += __shfl_xor(l,8);
    linv[r] = (l > 0.f) ? 1.0f/l : 0.f;
  }
  size_t obase = (size_t)(b*Ss + q0 + wave*16);
  #pragma unroll
  for (int nt=0; nt<2; nt++)
    #pragma unroll
    for (int r=0; r<4; r++)
      AO[(obase + quad*4 + r)*256 + h*32 + nt*16 + l15] = f2bf(O[nt][r]*linv[r]);
}

// ---------------- out projection + final softmax ------------------------------
__global__ __launch_bounds__(256) void k_logits(const float* __restrict__ T,
    const float* __restrict__ oW, const float* __restrict__ ob, float* __restrict__ L)
{
  int row  = blockIdx.x*4 + (threadIdx.x>>6);
  int lane = threadIdx.x & 63;
  float4 tv = ((const float4*)(T + (size_t)row*Hh))[lane];
  float4 wv = ((const float4*)oW)[lane];
  float s = tv.x*wv.x + tv.y*wv.y + tv.z*wv.z + tv.w*wv.w;
  #pragma unroll
  for (int o=32;o>0;o>>=1) s += __shfl_xor(s,o);
  if (lane==0) L[row] = s + ob[0];
}

__global__ __launch_bounds__(256) void k_final(const float* __restrict__ L,
    const float* __restrict__ valid, float* __restrict__ out)
{
  __shared__ float wsum[4];
  int b = blockIdx.x, t = threadIdx.x;
  float e0 = __expf(L[b*Ss + t      ]) * valid[b*Ss + t      ];
  float e1 = __expf(L[b*Ss + 256 + t]) * valid[b*Ss + 256 + t];
  float s = e0 + e1;
  #pragma unroll
  for (int o=32;o>0;o>>=1) s += __shfl_xor(s,o);
  if ((t&63)==0) wsum[t>>6] = s;
  __syncthreads();
  float tot = wsum[0]+wsum[1]+wsum[2]+wsum[3];
  out[b*Ss + t      ] = e0/tot;
  out[b*Ss + 256 + t] = e1/tot;
}

// ============================================================================
extern "C" void kernel_launch(void* const* d_in, const int* in_sizes, int n_in,
                              void* d_out, int out_size, void* d_ws, size_t ws_size,
                              hipStream_t stream)
{
  #define F(i) ((const float*)d_in[(i)])
  // Dict order vs signature order differ for d_ln1 vs d_eq..d_eo block.
  bool sig = (in_sizes[33] == 256);
  const float* d_eqW  = F(sig?35:33); const float* d_eqb  = F(sig?36:34);
  const float* d_ekW  = F(sig?37:35); const float* d_ekb  = F(sig?38:36);
  const float* d_evW  = F(sig?39:37); const float* d_evb  = F(sig?40:38);
  const float* d_eoW  = F(sig?41:39); const float* d_eob  = F(sig?42:40);
  const float* d_ln1g = F(sig?33:41); const float* d_ln1b = F(sig?34:42);

  // ---- workspace carve-up (~226.6 MB) ----
  char* w = (char*)d_ws;
  float*  P0 = (float*)w;  w += (size_t)Mm*Hh*4;   // 64 MiB
  float*  P1 = (float*)w;  w += (size_t)Mm*Hh*4;   // 64 MiB
  bf16_t* H0 = (bf16_t*)w; w += (size_t)Mm*Hh*2;   // 32 MiB (Q / AO / gelu)
  bf16_t* H1 = (bf16_t*)w;                          // 32 MiB (K / proj outs)
  bf16_t* xs = (bf16_t*)w; w += (size_t)Mm*Hh*2;   // xs aliases H1 head (dead after emb)
  bf16_t* H2 = (bf16_t*)w;                          // 32 MiB (VT layout)
  bf16_t* xt = (bf16_t*)w; w += (size_t)Mm*Hh*2;   // xt aliases H2 head
  bf16_t* Wa = (bf16_t*)w; w += (size_t)(2*16384 + 16*65536)*2;  // 2.1 MiB arena
  float*  valid  = (float*)w; w += (size_t)Mm*4;
  float*  logits = (float*)w; w += (size_t)Mm*4;
  float* out = (float*)d_out;

  // arena offsets
  unsigned o_sem = 0, o_tem = 16384;
  unsigned o_w[16]; for (int i=0;i<16;i++) o_w[i] = 32768 + i*65536u;
  // order: e_q e_k e_v e_o e_f1 e_f2 d_sq d_sk d_sv d_so d_eq d_ek d_ev d_eo d_f1 d_f2
  Prep18 pp;
  const float* srcs[18] = { F(5), F(7), F(9), F(11), F(13), F(15), F(19), F(21),
                            F(25), F(27), F(29), F(31), d_eqW, d_ekW, d_evW, d_eoW,
                            F(45), F(47) };
  unsigned offs[18] = { o_sem, o_tem, o_w[0],o_w[1],o_w[2],o_w[3],o_w[4],o_w[5],
                        o_w[6],o_w[7],o_w[8],o_w[9],o_w[10],o_w[11],o_w[12],o_w[13],
                        o_w[14],o_w[15] };
  for (int i=0;i<18;i++){ pp.d[i].s = srcs[i]; pp.d[i].off = offs[i]; pp.d[i].K = (i<2)?64:256; }

  dim3 blk(256);
  dim3 gLN(Mm/4);
  dim3 gG(4, Mm/128);
  dim3 gA(Bb*NHh*(Ss/64));
  dim3 gP(256, 18);

  k_prep<<<gP, blk, 0, stream>>>(pp, Wa);
  k_ln0<<<gLN, blk, 0, stream>>>(F(0), F(1),F(2), F(3),F(4), xs, xt, valid);

  k_gemm<0,0,1><<<gG, blk, 0, stream>>>(xs, Wa+o_sem, F(6), P0, 64);   // embs_src
  k_gemm<0,0,1><<<gG, blk, 0, stream>>>(xt, Wa+o_tem, F(8), P1, 64);   // embs_trg

  // ---- encoder ----
  k_gemm<1,0,0><<<gG, blk, 0, stream>>>(P0, Wa+o_w[0], F(10), H0, 256);  // Q
  k_gemm<1,0,0><<<gG, blk, 0, stream>>>(P0, Wa+o_w[1], F(12), H1, 256);  // K
  k_gemm<1,0,2><<<gG, blk, 0, stream>>>(P0, Wa+o_w[2], F(14), H2, 256);  // V -> VT
  k_attn<<<gA, blk, 0, stream>>>(H0, H1, H2, valid, H0);
  k_gemm<0,0,0><<<gG, blk, 0, stream>>>(H0, Wa+o_w[3], F(16), H1, 256);  // O proj
  k_add_ln<<<gLN, blk, 0, stream>>>(P0, H1, F(17), F(18), P0);           // x
  k_gemm<1,1,0><<<gG, blk, 0, stream>>>(P0, Wa+o_w[4], F(20), H0, 256);  // gelu(f1)
  k_gemm<0,0,0><<<gG, blk, 0, stream>>>(H0, Wa+o_w[5], F(22), H1, 256);  // f2
  k_add_ln<<<gLN, blk, 0, stream>>>(P0, H1, F(23), F(24), P0);           // enc_src

  // ---- decoder self-attention ----
  k_gemm<1,0,0><<<gG, blk, 0, stream>>>(P1, Wa+o_w[6], F(26), H0, 256);  // Q
  k_gemm<1,0,0><<<gG, blk, 0, stream>>>(P1, Wa+o_w[7], F(28), H1, 256);  // K
  k_gemm<1,0,2><<<gG, blk, 0, stream>>>(P1, Wa+o_w[8], F(30), H2, 256);  // V -> VT
  k_attn<<<gA, blk, 0, stream>>>(H0, H1, H2, valid, H0);
  k_gemm<0,0,0><<<gG, blk, 0, stream>>>(H0, Wa+o_w[9], F(32), H1, 256);  // O proj
  k_add_ln<<<gLN, blk, 0, stream>>>(P1, H1, d_ln1g, d_ln1b, P1);         // t

  // ---- decoder cross-attention ----
  k_gemm<1,0,0><<<gG, blk, 0, stream>>>(P1, Wa+o_w[10], d_eqb, H0, 256); // Q from t
  k_gemm<1,0,0><<<gG, blk, 0, stream>>>(P0, Wa+o_w[11], d_ekb, H1, 256); // K from enc
  k_gemm<1,0,2><<<gG, blk, 0, stream>>>(P0, Wa+o_w[12], d_evb, H2, 256); // V -> VT
  k_attn<<<gA, blk, 0, stream>>>(H0, H1, H2, valid, H0);
  k_gemm<0,0,0><<<gG, blk, 0, stream>>>(H0, Wa+o_w[13], d_eob, H1, 256); // O proj
  k_add_ln<<<gLN, blk, 0, stream>>>(P1, H1, F(43), F(44), P1);           // t

  // ---- decoder FFN ----
  k_gemm<1,1,0><<<gG, blk, 0, stream>>>(P1, Wa+o_w[14], F(46), H0, 256); // gelu(f1)
  k_gemm<0,0,0><<<gG, blk, 0, stream>>>(H0, Wa+o_w[15], F(48), H1, 256); // f2
  k_add_ln<<<gLN, blk, 0, stream>>>(P1, H1, F(49), F(50), P1);           // t

  // ---- output head ----
  k_logits<<<gLN, blk, 0, stream>>>(P1, F(51), F(52), logits);
  k_final<<<dim3(Bb), blk, 0, stream>>>(logits, valid, out);
  #undef F
}

// Round 4
// 1988.480 us; speedup vs baseline: 2.4615x; 1.0223x over previous
//
#include <hip/hip_runtime.h>

// ============================================================================
// TransformerChoiceNet forward. Round 4: reuse + fusion.
// - k_attn: block per (b,h); K slice staged in LDS once; VT via L1; q-tile
//   pairs share bK/bV frags. Fetch ~96 MB/dispatch (was 283).
// - k_gemm: block 64m x 256n (wave 16m x 256n, acc[16]) -> A fetched once.
//   Epilogues: plain bf16 / gelu / VT layout / fused residual+LN (bf16 P) /
//   fused residual+LN+logits-dot.
// - Residual streams bf16 (LN math fp32 in-register).
// Workspace ~163 MiB.
// ============================================================================

#define Bb  128
#define Ss  512
#define Hh  256
#define NHh 8
#define Mm  (Bb*Ss)

typedef unsigned short bf16_t;
typedef __attribute__((ext_vector_type(8))) short short8;
typedef __attribute__((ext_vector_type(4))) float f32x4;

__device__ __forceinline__ float bf2f(bf16_t h){
  union { unsigned int u; float f; } v; v.u = ((unsigned int)h)<<16; return v.f;
}
__device__ __forceinline__ bf16_t f2bf(float f){
  union { float f; unsigned int u; } v; v.f = f;
  unsigned int r = (v.u + 0x7fffu + ((v.u>>16)&1u)) >> 16;   // RNE
  return (bf16_t)r;
}
__device__ __forceinline__ short8 ld_bf8(const bf16_t* p){   // 16B load
  union { uint4 u; short8 s; } v; v.u = *(const uint4*)p; return v.s;
}
__device__ __forceinline__ float gelu_f(float x){
  float u = 0.7978845608028654f*(x + 0.044715f*x*x*x);
  return 0.5f*x*(1.0f + tanhf(u));
}

// ---------------- weight prep: fp32 W[k][n] -> bf16 Wt[n][k] ------------------
struct PrepDesc { const float* s; unsigned off; int K; };
struct Prep18  { PrepDesc d[18]; };

__global__ __launch_bounds__(256) void k_prep(Prep18 p, bf16_t* __restrict__ arena)
{
  PrepDesc dd = p.d[blockIdx.y];
  int i = blockIdx.x*256 + threadIdx.x;
  if (i < dd.K*256){
    int k = i>>8, n = i&255;
    arena[dd.off + n*dd.K + k] = f2bf(dd.s[i]);
  }
}

// ---------------- LN0 (two gains) + valid mask; bf16 out ----------------------
__global__ __launch_bounds__(256) void k_ln0(const float* __restrict__ src,
    const float* __restrict__ gs, const float* __restrict__ bs,
    const float* __restrict__ gt, const float* __restrict__ bt,
    bf16_t* __restrict__ xs, bf16_t* __restrict__ xt, float* __restrict__ valid)
{
  int row  = blockIdx.x*4 + (threadIdx.x>>6);
  int lane = threadIdx.x & 63;
  float x = src[(size_t)row*64 + lane];
  float s = x;
  #pragma unroll
  for (int o=32;o>0;o>>=1) s += __shfl_xor(s,o);
  float mean = s*(1.0f/64.0f);
  float d = x - mean;
  float ss = d*d;
  #pragma unroll
  for (int o=32;o>0;o>>=1) ss += __shfl_xor(ss,o);
  float r = rsqrtf(ss*(1.0f/64.0f) + 1e-5f);
  float xn = d*r;
  xs[(size_t)row*64+lane] = f2bf(xn*gs[lane] + bs[lane]);
  xt[(size_t)row*64+lane] = f2bf(xn*gt[lane] + bt[lane]);
  if (lane==0) valid[row] = (s != 0.0f) ? 1.0f : 0.0f;
}

// ---------------- MFMA GEMM: block 64m x 256n, wave 16m x 256n ----------------
// OUTM: 0 bf16 C [M,256] (EPI 0/1) | 2 bf16 VT[b][n][s] | 3 LN(Pres+(acc+b))
// -> bf16 P | 5 like 3 but dot with outW -> fp32 logits (no P write).
template<int EPI, int OUTM>
__global__ __launch_bounds__(256,2) void k_gemm(const bf16_t* __restrict__ A,
    const bf16_t* __restrict__ Wt, const float* __restrict__ bias,
    void* __restrict__ Cv, const bf16_t* __restrict__ Pres,
    const float* __restrict__ g, const float* __restrict__ bb,
    const float* __restrict__ oW, const float* __restrict__ obp, int K)
{
  int t = threadIdx.x, wave = t>>6, lane = t&63, l15 = lane&15, quad = lane>>4;
  int m0 = blockIdx.x*64 + wave*16;
  f32x4 z = {0.f,0.f,0.f,0.f};
  f32x4 acc[16] = {z,z,z,z,z,z,z,z,z,z,z,z,z,z,z,z};

  const bf16_t* Ar = A + (size_t)(m0 + l15)*K + quad*8;
  for (int kc=0; kc<K; kc+=32){
    short8 a = ld_bf8(Ar + kc);
    #pragma unroll
    for (int nt=0; nt<16; nt++){
      short8 bfr = ld_bf8(Wt + (size_t)(nt*16+l15)*K + kc + quad*8);
      acc[nt] = __builtin_amdgcn_mfma_f32_16x16x32_bf16(a, bfr, acc[nt], 0,0,0);
    }
  }

  float bv[16];
  #pragma unroll
  for (int nt=0; nt<16; nt++) bv[nt] = bias[nt*16 + l15];

  if (OUTM==0 || OUTM==2){
    #pragma unroll
    for (int nt=0; nt<16; nt++)
      #pragma unroll
      for (int r=0; r<4; r++){
        int row = m0 + quad*4 + r;
        int col = nt*16 + l15;
        float v = acc[nt][r] + bv[nt];
        if (EPI==1) v = gelu_f(v);
        if (OUTM==0) ((bf16_t*)Cv)[(size_t)row*256 + col] = f2bf(v);
        else         ((bf16_t*)Cv)[((size_t)(row>>9)*256 + col)*512 + (row&511)] = f2bf(v);
      }
  } else {
    float gv[16], bbv[16], wv[16];
    #pragma unroll
    for (int nt=0; nt<16; nt++){ gv[nt] = g[nt*16+l15]; bbv[nt] = bb[nt*16+l15]; }
    if (OUTM==5)
      #pragma unroll
      for (int nt=0; nt<16; nt++) wv[nt] = oW[nt*16+l15];
    #pragma unroll
    for (int r=0; r<4; r++){
      int row = m0 + quad*4 + r;
      const bf16_t* pr = Pres + (size_t)row*256;
      float v[16], sum = 0.f;
      #pragma unroll
      for (int nt=0; nt<16; nt++){
        v[nt] = acc[nt][r] + bv[nt] + bf2f(pr[nt*16+l15]);
        sum += v[nt];
      }
      sum += __shfl_xor(sum,1); sum += __shfl_xor(sum,2);
      sum += __shfl_xor(sum,4); sum += __shfl_xor(sum,8);
      float mean = sum*(1.0f/256.0f);
      float ss = 0.f;
      #pragma unroll
      for (int nt=0; nt<16; nt++){ float d = v[nt]-mean; ss += d*d; }
      ss += __shfl_xor(ss,1); ss += __shfl_xor(ss,2);
      ss += __shfl_xor(ss,4); ss += __shfl_xor(ss,8);
      float rstd = rsqrtf(ss*(1.0f/256.0f) + 1e-5f);
      if (OUTM==3){
        bf16_t* po = (bf16_t*)Cv + (size_t)row*256;
        #pragma unroll
        for (int nt=0; nt<16; nt++)
          po[nt*16+l15] = f2bf((v[nt]-mean)*rstd*gv[nt] + bbv[nt]);
      } else {
        float s2 = 0.f;
        #pragma unroll
        for (int nt=0; nt<16; nt++)
          s2 += ((v[nt]-mean)*rstd*gv[nt] + bbv[nt]) * wv[nt];
        s2 += __shfl_xor(s2,1); s2 += __shfl_xor(s2,2);
        s2 += __shfl_xor(s2,4); s2 += __shfl_xor(s2,8);
        if (l15==0) ((float*)Cv)[row] = s2 + obp[0];
      }
    }
  }
}

// ---------------- MFMA attention: block per (b,h) -----------------------------
// Q/K/AO bf16 [M,256] head slice; VT bf16 [B][256][512]. AO aliases Qm safely:
// all Q frags preloaded before any AO write; blocks own disjoint regions.
__global__ __launch_bounds__(256) void k_attn(const bf16_t* __restrict__ Qm,
    const bf16_t* __restrict__ Km, const bf16_t* __restrict__ VT,
    const float* __restrict__ valid, bf16_t* __restrict__ AO)
{
  __shared__ bf16_t Ksl[512][40];       // stride 40: 16B-aligned rows, uniform banks
  __shared__ bf16_t Pbuf[4][2][16][40];
  __shared__ float  Smask[512];
  int t = threadIdx.x, wave = t>>6, lane = t&63, l15 = lane&15, quad = lane>>4;
  int h = blockIdx.x, b = blockIdx.y;
  const float scale = 0.17677669529663687f;   // 1/sqrt(32)

  Smask[t]     = (valid[b*Ss + t      ] != 0.f) ? 0.f : -1e10f;
  Smask[t+256] = (valid[b*Ss + t + 256] != 0.f) ? 0.f : -1e10f;
  #pragma unroll
  for (int i=0; i<8; i++){
    int idx = t + i*256;
    int r = idx>>2, c8 = (idx&3)<<3;
    *(uint4*)&Ksl[r][c8] = *(const uint4*)(Km + (size_t)(b*Ss + r)*256 + h*32 + c8);
  }
  __syncthreads();

  short8 aQ[8];
  #pragma unroll
  for (int j=0; j<8; j++)
    aQ[j] = ld_bf8(Qm + (size_t)(b*Ss + (wave*8+j)*16 + l15)*256 + h*32 + quad*8);
  const bf16_t* Vb = VT + ((size_t)b*256 + h*32)*512;

  f32x4 z = {0.f,0.f,0.f,0.f};
  #pragma unroll 1
  for (int p=0; p<4; p++){
    f32x4 O0[2] = {z,z}, O1[2] = {z,z};
    float ls0[4] = {0.f,0.f,0.f,0.f}, ls1[4] = {0.f,0.f,0.f,0.f};
    for (int kt2=0; kt2<16; kt2++){
      #pragma unroll
      for (int half=0; half<2; half++){
        int ktile = kt2*2 + half;
        short8 bK = ld_bf8(&Ksl[ktile*16 + l15][quad*8]);
        f32x4 s0 = __builtin_amdgcn_mfma_f32_16x16x32_bf16(aQ[2*p  ], bK, z, 0,0,0);
        f32x4 s1 = __builtin_amdgcn_mfma_f32_16x16x32_bf16(aQ[2*p+1], bK, z, 0,0,0);
        float mb = Smask[ktile*16 + l15];
        #pragma unroll
        for (int r=0; r<4; r++){
          float p0 = __expf(s0[r]*scale + mb);   // no max-sub: scores O(5); masked->0
          float p1 = __expf(s1[r]*scale + mb);
          ls0[r] += p0; ls1[r] += p1;
          Pbuf[wave][0][quad*4+r][half*16+l15] = f2bf(p0);
          Pbuf[wave][1][quad*4+r][half*16+l15] = f2bf(p1);
        }
      }
      short8 aP0 = ld_bf8(&Pbuf[wave][0][l15][quad*8]);
      short8 aP1 = ld_bf8(&Pbuf[wave][1][l15][quad*8]);
      #pragma unroll
      for (int nt=0; nt<2; nt++){
        short8 bV = ld_bf8(Vb + (size_t)(nt*16+l15)*512 + kt2*32 + quad*8);
        O0[nt] = __builtin_amdgcn_mfma_f32_16x16x32_bf16(aP0, bV, O0[nt], 0,0,0);
        O1[nt] = __builtin_amdgcn_mfma_f32_16x16x32_bf16(aP1, bV, O1[nt], 0,0,0);
      }
    }
    float i0[4], i1[4];
    #pragma unroll
    for (int r=0; r<4; r++){
      float l0 = ls0[r];
      l0 += __shfl_xor(l0,1); l0 += __shfl_xor(l0,2);
      l0 += __shfl_xor(l0,4); l0 += __shfl_xor(l0,8);
      i0[r] = (l0 > 0.f) ? 1.0f/l0 : 0.f;
      float l1 = ls1[r];
      l1 += __shfl_xor(l1,1); l1 += __shfl_xor(l1,2);
      l1 += __shfl_xor(l1,4); l1 += __shfl_xor(l1,8);
      i1[r] = (l1 > 0.f) ? 1.0f/l1 : 0.f;
    }
    size_t r0 = (size_t)(b*Ss + (wave*8 + 2*p  )*16);
    size_t r1 = (size_t)(b*Ss + (wave*8 + 2*p+1)*16);
    #pragma unroll
    for (int nt=0; nt<2; nt++)
      #pragma unroll
      for (int r=0; r<4; r++){
        AO[(r0 + quad*4 + r)*256 + h*32 + nt*16 + l15] = f2bf(O0[nt][r]*i0[r]);
        AO[(r1 + quad*4 + r)*256 + h*32 + nt*16 + l15] = f2bf(O1[nt][r]*i1[r]);
      }
  }
}

// ---------------- final: p = exp(logits)*valid, normalize per batch -----------
__global__ __launch_bounds__(256) void k_final(const float* __restrict__ L,
    const float* __restrict__ valid, float* __restrict__ out)
{
  __shared__ float wsum[4];
  int b = blockIdx.x, t = threadIdx.x;
  float e0 = __expf(L[b*Ss + t      ]) * valid[b*Ss + t      ];
  float e1 = __expf(L[b*Ss + 256 + t]) * valid[b*Ss + 256 + t];
  float s = e0 + e1;
  #pragma unroll
  for (int o=32;o>0;o>>=1) s += __shfl_xor(s,o);
  if ((t&63)==0) wsum[t>>6] = s;
  __syncthreads();
  float tot = wsum[0]+wsum[1]+wsum[2]+wsum[3];
  out[b*Ss + t      ] = e0/tot;
  out[b*Ss + 256 + t] = e1/tot;
}

// ============================================================================
extern "C" void kernel_launch(void* const* d_in, const int* in_sizes, int n_in,
                              void* d_out, int out_size, void* d_ws, size_t ws_size,
                              hipStream_t stream)
{
  #define F(i) ((const float*)d_in[(i)])
  bool sig = (in_sizes[33] == 256);   // signature order vs dict order
  const float* d_eqW  = F(sig?35:33); const float* d_eqb  = F(sig?36:34);
  const float* d_ekW  = F(sig?37:35); const float* d_ekb  = F(sig?38:36);
  const float* d_evW  = F(sig?39:37); const float* d_evb  = F(sig?40:38);
  const float* d_eoW  = F(sig?41:39); const float* d_eob  = F(sig?42:40);
  const float* d_ln1g = F(sig?33:41); const float* d_ln1b = F(sig?34:42);

  // ---- workspace (~163 MiB) ----
  char* w = (char*)d_ws;
  bf16_t* P0 = (bf16_t*)w; w += (size_t)Mm*Hh*2;   // 32 MiB residual (enc)
  bf16_t* P1 = (bf16_t*)w; w += (size_t)Mm*Hh*2;   // 32 MiB residual (dec)
  bf16_t* H0 = (bf16_t*)w; w += (size_t)Mm*Hh*2;   // 32 MiB Q / AO / gelu
  bf16_t* H1 = (bf16_t*)w;                          // 32 MiB K / xs alias
  bf16_t* xs = (bf16_t*)w; w += (size_t)Mm*Hh*2;
  bf16_t* H2 = (bf16_t*)w;                          // 32 MiB VT / xt alias
  bf16_t* xt = (bf16_t*)w; w += (size_t)Mm*Hh*2;
  bf16_t* Wa = (bf16_t*)w; w += (size_t)(2*16384 + 16*65536)*2;  // 2.1 MiB
  float*  valid  = (float*)w; w += (size_t)Mm*4;
  float*  logits = (float*)w; w += (size_t)Mm*4;
  float* out = (float*)d_out;

  unsigned o_sem = 0, o_tem = 16384;
  unsigned o_w[16]; for (int i=0;i<16;i++) o_w[i] = 32768 + i*65536u;
  Prep18 pp;
  const float* srcs[18] = { F(5), F(7), F(9), F(11), F(13), F(15), F(19), F(21),
                            F(25), F(27), F(29), F(31), d_eqW, d_ekW, d_evW, d_eoW,
                            F(45), F(47) };
  unsigned offs[18] = { o_sem, o_tem, o_w[0],o_w[1],o_w[2],o_w[3],o_w[4],o_w[5],
                        o_w[6],o_w[7],o_w[8],o_w[9],o_w[10],o_w[11],o_w[12],o_w[13],
                        o_w[14],o_w[15] };
  for (int i=0;i<18;i++){ pp.d[i].s = srcs[i]; pp.d[i].off = offs[i]; pp.d[i].K = (i<2)?64:256; }

  dim3 blk(256);
  dim3 gLN(Mm/4);
  dim3 gG(Mm/64);
  dim3 gA(NHh, Bb);
  dim3 gP(256, 18);
  const float* NF = nullptr; const bf16_t* NB = nullptr;

  k_prep<<<gP, blk, 0, stream>>>(pp, Wa);
  k_ln0<<<gLN, blk, 0, stream>>>(F(0), F(1),F(2), F(3),F(4), xs, xt, valid);

  k_gemm<0,0><<<gG, blk, 0, stream>>>(xs, Wa+o_sem, F(6), P0, NB,NF,NF,NF,NF, 64);
  k_gemm<0,0><<<gG, blk, 0, stream>>>(xt, Wa+o_tem, F(8), P1, NB,NF,NF,NF,NF, 64);

  // ---- encoder ----
  k_gemm<0,0><<<gG, blk, 0, stream>>>(P0, Wa+o_w[0], F(10), H0, NB,NF,NF,NF,NF, 256);
  k_gemm<0,0><<<gG, blk, 0, stream>>>(P0, Wa+o_w[1], F(12), H1, NB,NF,NF,NF,NF, 256);
  k_gemm<0,2><<<gG, blk, 0, stream>>>(P0, Wa+o_w[2], F(14), H2, NB,NF,NF,NF,NF, 256);
  k_attn<<<gA, blk, 0, stream>>>(H0, H1, H2, valid, H0);
  k_gemm<0,3><<<gG, blk, 0, stream>>>(H0, Wa+o_w[3], F(16), P0, P0, F(17),F(18), NF,NF, 256);
  k_gemm<1,0><<<gG, blk, 0, stream>>>(P0, Wa+o_w[4], F(20), H0, NB,NF,NF,NF,NF, 256);
  k_gemm<0,3><<<gG, blk, 0, stream>>>(H0, Wa+o_w[5], F(22), P0, P0, F(23),F(24), NF,NF, 256);

  // ---- decoder self-attention ----
  k_gemm<0,0><<<gG, blk, 0, stream>>>(P1, Wa+o_w[6], F(26), H0, NB,NF,NF,NF,NF, 256);
  k_gemm<0,0><<<gG, blk, 0, stream>>>(P1, Wa+o_w[7], F(28), H1, NB,NF,NF,NF,NF, 256);
  k_gemm<0,2><<<gG, blk, 0, stream>>>(P1, Wa+o_w[8], F(30), H2, NB,NF,NF,NF,NF, 256);
  k_attn<<<gA, blk, 0, stream>>>(H0, H1, H2, valid, H0);
  k_gemm<0,3><<<gG, blk, 0, stream>>>(H0, Wa+o_w[9], F(32), P1, P1, d_ln1g,d_ln1b, NF,NF, 256);

  // ---- decoder cross-attention ----
  k_gemm<0,0><<<gG, blk, 0, stream>>>(P1, Wa+o_w[10], d_eqb, H0, NB,NF,NF,NF,NF, 256);
  k_gemm<0,0><<<gG, blk, 0, stream>>>(P0, Wa+o_w[11], d_ekb, H1, NB,NF,NF,NF,NF, 256);
  k_gemm<0,2><<<gG, blk, 0, stream>>>(P0, Wa+o_w[12], d_evb, H2, NB,NF,NF,NF,NF, 256);
  k_attn<<<gA, blk, 0, stream>>>(H0, H1, H2, valid, H0);
  k_gemm<0,3><<<gG, blk, 0, stream>>>(H0, Wa+o_w[13], d_eob, P1, P1, F(43),F(44), NF,NF, 256);

  // ---- decoder FFN + fused ln3 + logits ----
  k_gemm<1,0><<<gG, blk, 0, stream>>>(P1, Wa+o_w[14], F(46), H0, NB,NF,NF,NF,NF, 256);
  k_gemm<0,5><<<gG, blk, 0, stream>>>(H0, Wa+o_w[15], F(48), logits, P1, F(49),F(50), F(51),F(52), 256);

  k_final<<<dim3(Bb), blk, 0, stream>>>(logits, valid, out);
  #undef F
}

// Round 5
// 1243.440 us; speedup vs baseline: 3.9364x; 1.5992x over previous
//
#include <hip/hip_runtime.h>

// ============================================================================
// TransformerChoiceNet forward. Round 5: m97-style MFMA GEMM with
// global_load_lds staging (frag-ordered LDS), full-row blocks for LN fusion.
// Attention unchanged from round 4 (next target).
// B=128 S=512 D=64 H=256 NH=8 HD=32, M=B*S=65536.
// ============================================================================

#define Bb  128
#define Ss  512
#define Hh  256
#define NHh 8
#define Mm  (Bb*Ss)

typedef unsigned short bf16_t;
typedef __attribute__((ext_vector_type(8))) short short8;
typedef __attribute__((ext_vector_type(4))) float f32x4;

__device__ __forceinline__ float bf2f(bf16_t h){
  union { unsigned int u; float f; } v; v.u = ((unsigned int)h)<<16; return v.f;
}
__device__ __forceinline__ bf16_t f2bf(float f){
  union { float f; unsigned int u; } v; v.f = f;
  unsigned int r = (v.u + 0x7fffu + ((v.u>>16)&1u)) >> 16;   // RNE
  return (bf16_t)r;
}
__device__ __forceinline__ short8 ld_bf8(const bf16_t* p){   // 16B load
  union { uint4 u; short8 s; } v; v.u = *(const uint4*)p; return v.s;
}
__device__ __forceinline__ void gload16(const bf16_t* g, bf16_t* l){
  // async global->LDS, 16B/lane; LDS dest = wave-uniform base + lane*16
  __builtin_amdgcn_global_load_lds(
      (const __attribute__((address_space(1))) void*)g,
      (__attribute__((address_space(3))) void*)l, 16, 0, 0);
}
__device__ __forceinline__ float gelu_f(float x){
  float u = 0.7978845608028654f*(x + 0.044715f*x*x*x);
  return 0.5f*x*(1.0f + tanhf(u));
}

// ---------------- weight prep: fp32 W[k][n] -> bf16 Wt[n][k] ------------------
struct PrepDesc { const float* s; unsigned off; int K; };
struct Prep18  { PrepDesc d[18]; };

__global__ __launch_bounds__(256) void k_prep(Prep18 p, bf16_t* __restrict__ arena)
{
  PrepDesc dd = p.d[blockIdx.y];
  int i = blockIdx.x*256 + threadIdx.x;
  if (i < dd.K*256){
    int k = i>>8, n = i&255;
    arena[dd.off + n*dd.K + k] = f2bf(dd.s[i]);
  }
}

// ---------------- LN0 (two gains) + valid mask; bf16 out ----------------------
__global__ __launch_bounds__(256) void k_ln0(const float* __restrict__ src,
    const float* __restrict__ gs, const float* __restrict__ bs,
    const float* __restrict__ gt, const float* __restrict__ bt,
    bf16_t* __restrict__ xs, bf16_t* __restrict__ xt, float* __restrict__ valid)
{
  int row  = blockIdx.x*4 + (threadIdx.x>>6);
  int lane = threadIdx.x & 63;
  float x = src[(size_t)row*64 + lane];
  float s = x;
  #pragma unroll
  for (int o=32;o>0;o>>=1) s += __shfl_xor(s,o);
  float mean = s*(1.0f/64.0f);
  float d = x - mean;
  float ss = d*d;
  #pragma unroll
  for (int o=32;o>0;o>>=1) ss += __shfl_xor(ss,o);
  float r = rsqrtf(ss*(1.0f/64.0f) + 1e-5f);
  float xn = d*r;
  xs[(size_t)row*64+lane] = f2bf(xn*gs[lane] + bs[lane]);
  xt[(size_t)row*64+lane] = f2bf(xn*gt[lane] + bt[lane]);
  if (lane==0) valid[row] = (s != 0.0f) ? 1.0f : 0.0f;
}

// ---------------- MFMA GEMM: block 64m x 256n, BK=64, LDS staged --------------
// As: 8 frag-blocks (kc32*4+mt), Bs: 32 frag-blocks (kc32*16+gnt); each block
// is 64 lanes x 16B in lane order -> ds_read_b128 base+lane*16, conflict-free.
// Wave w owns n-cols w*64..w*64+63 (gnt = w*4+nt). C row = m0+mt*16+quad*4+r,
// col = w*64+nt*16+l15.
// OUTM: 0 bf16 C[M,256] (EPI 0/1) | 2 bf16 VT[b][n][s] |
//       3 LN(Pres+(acc+b)) -> bf16 P | 5 like 3 but dot outW -> fp32 logits.
template<int EPI, int OUTM>
__global__ __launch_bounds__(256,3) void k_gemm(const bf16_t* __restrict__ A,
    const bf16_t* __restrict__ Wt, const float* __restrict__ bias,
    void* __restrict__ Cv, const bf16_t* __restrict__ Pres,
    const float* __restrict__ g, const float* __restrict__ bb,
    const float* __restrict__ oW, const float* __restrict__ obp, int K)
{
  __shared__ bf16_t As[8*512];    // 8 KB
  __shared__ bf16_t Bs[32*512];   // 32 KB
  int t = threadIdx.x, w = t>>6, lane = t&63, l15 = lane&15, quad = lane>>4;
  int m0 = blockIdx.x*64;
  f32x4 z = {0.f,0.f,0.f,0.f};
  f32x4 acc[4][4] = {{z,z,z,z},{z,z,z,z},{z,z,z,z},{z,z,z,z}};

  for (int k0=0; k0<K; k0+=64){
    #pragma unroll
    for (int j=0; j<2; j++){                       // A: wave stages ids 2w,2w+1
      int id = 2*w + j; int kc32 = id>>2, mt = id&3;
      gload16(A + (size_t)(m0 + mt*16 + l15)*K + k0 + kc32*32 + quad*8,
              &As[id*512]);
    }
    #pragma unroll
    for (int j=0; j<8; j++){                       // B: wave stages ids 8w..8w+7
      int id = 8*w + j; int kc32 = id>>4, gnt = id&15;
      gload16(Wt + (size_t)(gnt*16 + l15)*K + k0 + kc32*32 + quad*8,
              &Bs[id*512]);
    }
    __syncthreads();                                // drain vmcnt + barrier
    #pragma unroll
    for (int kc=0; kc<2; kc++){
      short8 a[4], b[4];
      #pragma unroll
      for (int mt=0; mt<4; mt++) a[mt] = ld_bf8(&As[(kc*4+mt)*512 + lane*8]);
      #pragma unroll
      for (int nt=0; nt<4; nt++) b[nt] = ld_bf8(&Bs[(kc*16 + w*4 + nt)*512 + lane*8]);
      #pragma unroll
      for (int mt=0; mt<4; mt++)
        #pragma unroll
        for (int nt=0; nt<4; nt++)
          acc[mt][nt] = __builtin_amdgcn_mfma_f32_16x16x32_bf16(a[mt], b[nt], acc[mt][nt], 0,0,0);
    }
    __syncthreads();                                // LDS reuse next iter
  }

  float bv[4];
  #pragma unroll
  for (int nt=0; nt<4; nt++) bv[nt] = bias[w*64 + nt*16 + l15];

  if (OUTM==0 || OUTM==2){
    #pragma unroll
    for (int mt=0; mt<4; mt++)
      #pragma unroll
      for (int nt=0; nt<4; nt++)
        #pragma unroll
        for (int r=0; r<4; r++){
          int row = m0 + mt*16 + quad*4 + r;
          int col = w*64 + nt*16 + l15;
          float v = acc[mt][nt][r] + bv[nt];
          if (EPI==1) v = gelu_f(v);
          if (OUTM==0) ((bf16_t*)Cv)[(size_t)row*256 + col] = f2bf(v);
          else         ((bf16_t*)Cv)[((size_t)(row>>9)*256 + col)*512 + (row&511)] = f2bf(v);
        }
  } else {
    // fused residual + LN (+ optional logits dot). Cross-wave row reduction
    // through LDS (reuse As arena; loop's trailing barrier fences it).
    float* RedS = (float*)As;          // [64][4]
    float* RedQ = RedS + 256;          // [64][4]
    #pragma unroll
    for (int mt=0; mt<4; mt++)
      #pragma unroll
      for (int r=0; r<4; r++){
        int row = m0 + mt*16 + quad*4 + r;
        const bf16_t* pr = Pres + (size_t)row*256;
        float s = 0.f, q = 0.f;
        #pragma unroll
        for (int nt=0; nt<4; nt++){
          float v = acc[mt][nt][r] + bv[nt] + bf2f(pr[w*64 + nt*16 + l15]);
          s += v; q += v*v;
        }
        s += __shfl_xor(s,1); s += __shfl_xor(s,2);
        s += __shfl_xor(s,4); s += __shfl_xor(s,8);
        q += __shfl_xor(q,1); q += __shfl_xor(q,2);
        q += __shfl_xor(q,4); q += __shfl_xor(q,8);
        if (l15==0){
          int rr = mt*16 + quad*4 + r;
          RedS[rr*4 + w] = s; RedQ[rr*4 + w] = q;
        }
      }
    __syncthreads();

    float gv[4], bbv[4], wv[4];
    #pragma unroll
    for (int nt=0; nt<4; nt++){ gv[nt] = g[w*64+nt*16+l15]; bbv[nt] = bb[w*64+nt*16+l15]; }
    if (OUTM==5)
      #pragma unroll
      for (int nt=0; nt<4; nt++) wv[nt] = oW[w*64+nt*16+l15];

    float s2p[4][4];   // logits partials per (mt,r)
    #pragma unroll
    for (int mt=0; mt<4; mt++)
      #pragma unroll
      for (int r=0; r<4; r++){
        int rr = mt*16 + quad*4 + r;
        int row = m0 + rr;
        float S = RedS[rr*4+0]+RedS[rr*4+1]+RedS[rr*4+2]+RedS[rr*4+3];
        float Q = RedQ[rr*4+0]+RedQ[rr*4+1]+RedQ[rr*4+2]+RedQ[rr*4+3];
        float mean = S*(1.0f/256.0f);
        float var  = Q*(1.0f/256.0f) - mean*mean;
        float rstd = rsqrtf(var + 1e-5f);
        const bf16_t* pr = Pres + (size_t)row*256;
        if (OUTM==3){
          bf16_t* po = (bf16_t*)Cv + (size_t)row*256;
          #pragma unroll
          for (int nt=0; nt<4; nt++){
            float v = acc[mt][nt][r] + bv[nt] + bf2f(pr[w*64 + nt*16 + l15]);
            po[w*64 + nt*16 + l15] = f2bf((v-mean)*rstd*gv[nt] + bbv[nt]);
          }
        } else {
          float s2 = 0.f;
          #pragma unroll
          for (int nt=0; nt<4; nt++){
            float v = acc[mt][nt][r] + bv[nt] + bf2f(pr[w*64 + nt*16 + l15]);
            s2 += ((v-mean)*rstd*gv[nt] + bbv[nt]) * wv[nt];
          }
          s2 += __shfl_xor(s2,1); s2 += __shfl_xor(s2,2);
          s2 += __shfl_xor(s2,4); s2 += __shfl_xor(s2,8);
          s2p[mt][r] = s2;
        }
      }
    if (OUTM==5){
      __syncthreads();      // done reading RedS/RedQ; reuse RedS
      #pragma unroll
      for (int mt=0; mt<4; mt++)
        #pragma unroll
        for (int r=0; r<4; r++)
          if (l15==0) RedS[(mt*16 + quad*4 + r)*4 + w] = s2p[mt][r];
      __syncthreads();
      if (w==0){
        float S = RedS[lane*4+0]+RedS[lane*4+1]+RedS[lane*4+2]+RedS[lane*4+3];
        ((float*)Cv)[m0 + lane] = S + obp[0];
      }
    }
  }
}

// ---------------- MFMA attention: block per (b,h) (unchanged round 4) ---------
__global__ __launch_bounds__(256) void k_attn(const bf16_t* __restrict__ Qm,
    const bf16_t* __restrict__ Km, const bf16_t* __restrict__ VT,
    const float* __restrict__ valid, bf16_t* __restrict__ AO)
{
  __shared__ bf16_t Ksl[512][40];
  __shared__ bf16_t Pbuf[4][2][16][40];
  __shared__ float  Smask[512];
  int t = threadIdx.x, wave = t>>6, lane = t&63, l15 = lane&15, quad = lane>>4;
  int h = blockIdx.x, b = blockIdx.y;
  const float scale = 0.17677669529663687f;   // 1/sqrt(32)

  Smask[t]     = (valid[b*Ss + t      ] != 0.f) ? 0.f : -1e10f;
  Smask[t+256] = (valid[b*Ss + t + 256] != 0.f) ? 0.f : -1e10f;
  #pragma unroll
  for (int i=0; i<8; i++){
    int idx = t + i*256;
    int r = idx>>2, c8 = (idx&3)<<3;
    *(uint4*)&Ksl[r][c8] = *(const uint4*)(Km + (size_t)(b*Ss + r)*256 + h*32 + c8);
  }
  __syncthreads();

  short8 aQ[8];
  #pragma unroll
  for (int j=0; j<8; j++)
    aQ[j] = ld_bf8(Qm + (size_t)(b*Ss + (wave*8+j)*16 + l15)*256 + h*32 + quad*8);
  const bf16_t* Vb = VT + ((size_t)b*256 + h*32)*512;

  f32x4 z = {0.f,0.f,0.f,0.f};
  #pragma unroll 1
  for (int p=0; p<4; p++){
    f32x4 O0[2] = {z,z}, O1[2] = {z,z};
    float ls0[4] = {0.f,0.f,0.f,0.f}, ls1[4] = {0.f,0.f,0.f,0.f};
    for (int kt2=0; kt2<16; kt2++){
      #pragma unroll
      for (int half=0; half<2; half++){
        int ktile = kt2*2 + half;
        short8 bK = ld_bf8(&Ksl[ktile*16 + l15][quad*8]);
        f32x4 s0 = __builtin_amdgcn_mfma_f32_16x16x32_bf16(aQ[2*p  ], bK, z, 0,0,0);
        f32x4 s1 = __builtin_amdgcn_mfma_f32_16x16x32_bf16(aQ[2*p+1], bK, z, 0,0,0);
        float mb = Smask[ktile*16 + l15];
        #pragma unroll
        for (int r=0; r<4; r++){
          float p0 = __expf(s0[r]*scale + mb);
          float p1 = __expf(s1[r]*scale + mb);
          ls0[r] += p0; ls1[r] += p1;
          Pbuf[wave][0][quad*4+r][half*16+l15] = f2bf(p0);
          Pbuf[wave][1][quad*4+r][half*16+l15] = f2bf(p1);
        }
      }
      short8 aP0 = ld_bf8(&Pbuf[wave][0][l15][quad*8]);
      short8 aP1 = ld_bf8(&Pbuf[wave][1][l15][quad*8]);
      #pragma unroll
      for (int nt=0; nt<2; nt++){
        short8 bV = ld_bf8(Vb + (size_t)(nt*16+l15)*512 + kt2*32 + quad*8);
        O0[nt] = __builtin_amdgcn_mfma_f32_16x16x32_bf16(aP0, bV, O0[nt], 0,0,0);
        O1[nt] = __builtin_amdgcn_mfma_f32_16x16x32_bf16(aP1, bV, O1[nt], 0,0,0);
      }
    }
    float i0[4], i1[4];
    #pragma unroll
    for (int r=0; r<4; r++){
      float l0 = ls0[r];
      l0 += __shfl_xor(l0,1); l0 += __shfl_xor(l0,2);
      l0 += __shfl_xor(l0,4); l0 += __shfl_xor(l0,8);
      i0[r] = (l0 > 0.f) ? 1.0f/l0 : 0.f;
      float l1 = ls1[r];
      l1 += __shfl_xor(l1,1); l1 += __shfl_xor(l1,2);
      l1 += __shfl_xor(l1,4); l1 += __shfl_xor(l1,8);
      i1[r] = (l1 > 0.f) ? 1.0f/l1 : 0.f;
    }
    size_t r0 = (size_t)(b*Ss + (wave*8 + 2*p  )*16);
    size_t r1 = (size_t)(b*Ss + (wave*8 + 2*p+1)*16);
    #pragma unroll
    for (int nt=0; nt<2; nt++)
      #pragma unroll
      for (int r=0; r<4; r++){
        AO[(r0 + quad*4 + r)*256 + h*32 + nt*16 + l15] = f2bf(O0[nt][r]*i0[r]);
        AO[(r1 + quad*4 + r)*256 + h*32 + nt*16 + l15] = f2bf(O1[nt][r]*i1[r]);
      }
  }
}

// ---------------- final: p = exp(logits)*valid, normalize per batch -----------
__global__ __launch_bounds__(256) void k_final(const float* __restrict__ L,
    const float* __restrict__ valid, float* __restrict__ out)
{
  __shared__ float wsum[4];
  int b = blockIdx.x, t = threadIdx.x;
  float e0 = __expf(L[b*Ss + t      ]) * valid[b*Ss + t      ];
  float e1 = __expf(L[b*Ss + 256 + t]) * valid[b*Ss + 256 + t];
  float s = e0 + e1;
  #pragma unroll
  for (int o=32;o>0;o>>=1) s += __shfl_xor(s,o);
  if ((t&63)==0) wsum[t>>6] = s;
  __syncthreads();
  float tot = wsum[0]+wsum[1]+wsum[2]+wsum[3];
  out[b*Ss + t      ] = e0/tot;
  out[b*Ss + 256 + t] = e1/tot;
}

// ============================================================================
extern "C" void kernel_launch(void* const* d_in, const int* in_sizes, int n_in,
                              void* d_out, int out_size, void* d_ws, size_t ws_size,
                              hipStream_t stream)
{
  #define F(i) ((const float*)d_in[(i)])
  bool sig = (in_sizes[33] == 256);   // signature order vs dict order
  const float* d_eqW  = F(sig?35:33); const float* d_eqb  = F(sig?36:34);
  const float* d_ekW  = F(sig?37:35); const float* d_ekb  = F(sig?38:36);
  const float* d_evW  = F(sig?39:37); const float* d_evb  = F(sig?40:38);
  const float* d_eoW  = F(sig?41:39); const float* d_eob  = F(sig?42:40);
  const float* d_ln1g = F(sig?33:41); const float* d_ln1b = F(sig?34:42);

  // ---- workspace (~163 MiB) ----
  char* w = (char*)d_ws;
  bf16_t* P0 = (bf16_t*)w; w += (size_t)Mm*Hh*2;   // 32 MiB residual (enc)
  bf16_t* P1 = (bf16_t*)w; w += (size_t)Mm*Hh*2;   // 32 MiB residual (dec)
  bf16_t* H0 = (bf16_t*)w; w += (size_t)Mm*Hh*2;   // 32 MiB Q / AO / gelu
  bf16_t* H1 = (bf16_t*)w;                          // 32 MiB K / xs alias
  bf16_t* xs = (bf16_t*)w; w += (size_t)Mm*Hh*2;
  bf16_t* H2 = (bf16_t*)w;                          // 32 MiB VT / xt alias
  bf16_t* xt = (bf16_t*)w; w += (size_t)Mm*Hh*2;
  bf16_t* Wa = (bf16_t*)w; w += (size_t)(2*16384 + 16*65536)*2;  // 2.1 MiB
  float*  valid  = (float*)w; w += (size_t)Mm*4;
  float*  logits = (float*)w; w += (size_t)Mm*4;
  float* out = (float*)d_out;

  unsigned o_sem = 0, o_tem = 16384;
  unsigned o_w[16]; for (int i=0;i<16;i++) o_w[i] = 32768 + i*65536u;
  Prep18 pp;
  const float* srcs[18] = { F(5), F(7), F(9), F(11), F(13), F(15), F(19), F(21),
                            F(25), F(27), F(29), F(31), d_eqW, d_ekW, d_evW, d_eoW,
                            F(45), F(47) };
  unsigned offs[18] = { o_sem, o_tem, o_w[0],o_w[1],o_w[2],o_w[3],o_w[4],o_w[5],
                        o_w[6],o_w[7],o_w[8],o_w[9],o_w[10],o_w[11],o_w[12],o_w[13],
                        o_w[14],o_w[15] };
  for (int i=0;i<18;i++){ pp.d[i].s = srcs[i]; pp.d[i].off = offs[i]; pp.d[i].K = (i<2)?64:256; }

  dim3 blk(256);
  dim3 gLN(Mm/4);
  dim3 gG(Mm/64);
  dim3 gA(NHh, Bb);
  dim3 gP(256, 18);
  const float* NF = nullptr; const bf16_t* NB = nullptr;

  k_prep<<<gP, blk, 0, stream>>>(pp, Wa);
  k_ln0<<<gLN, blk, 0, stream>>>(F(0), F(1),F(2), F(3),F(4), xs, xt, valid);

  k_gemm<0,0><<<gG, blk, 0, stream>>>(xs, Wa+o_sem, F(6), P0, NB,NF,NF,NF,NF, 64);
  k_gemm<0,0><<<gG, blk, 0, stream>>>(xt, Wa+o_tem, F(8), P1, NB,NF,NF,NF,NF, 64);

  // ---- encoder ----
  k_gemm<0,0><<<gG, blk, 0, stream>>>(P0, Wa+o_w[0], F(10), H0, NB,NF,NF,NF,NF, 256);
  k_gemm<0,0><<<gG, blk, 0, stream>>>(P0, Wa+o_w[1], F(12), H1, NB,NF,NF,NF,NF, 256);
  k_gemm<0,2><<<gG, blk, 0, stream>>>(P0, Wa+o_w[2], F(14), H2, NB,NF,NF,NF,NF, 256);
  k_attn<<<gA, blk, 0, stream>>>(H0, H1, H2, valid, H0);
  k_gemm<0,3><<<gG, blk, 0, stream>>>(H0, Wa+o_w[3], F(16), P0, P0, F(17),F(18), NF,NF, 256);
  k_gemm<1,0><<<gG, blk, 0, stream>>>(P0, Wa+o_w[4], F(20), H0, NB,NF,NF,NF,NF, 256);
  k_gemm<0,3><<<gG, blk, 0, stream>>>(H0, Wa+o_w[5], F(22), P0, P0, F(23),F(24), NF,NF, 256);

  // ---- decoder self-attention ----
  k_gemm<0,0><<<gG, blk, 0, stream>>>(P1, Wa+o_w[6], F(26), H0, NB,NF,NF,NF,NF, 256);
  k_gemm<0,0><<<gG, blk, 0, stream>>>(P1, Wa+o_w[7], F(28), H1, NB,NF,NF,NF,NF, 256);
  k_gemm<0,2><<<gG, blk, 0, stream>>>(P1, Wa+o_w[8], F(30), H2, NB,NF,NF,NF,NF, 256);
  k_attn<<<gA, blk, 0, stream>>>(H0, H1, H2, valid, H0);
  k_gemm<0,3><<<gG, blk, 0, stream>>>(H0, Wa+o_w[9], F(32), P1, P1, d_ln1g,d_ln1b, NF,NF, 256);

  // ---- decoder cross-attention ----
  k_gemm<0,0><<<gG, blk, 0, stream>>>(P1, Wa+o_w[10], d_eqb, H0, NB,NF,NF,NF,NF, 256);
  k_gemm<0,0><<<gG, blk, 0, stream>>>(P0, Wa+o_w[11], d_ekb, H1, NB,NF,NF,NF,NF, 256);
  k_gemm<0,2><<<gG, blk, 0, stream>>>(P0, Wa+o_w[12], d_evb, H2, NB,NF,NF,NF,NF, 256);
  k_attn<<<gA, blk, 0, stream>>>(H0, H1, H2, valid, H0);
  k_gemm<0,3><<<gG, blk, 0, stream>>>(H0, Wa+o_w[13], d_eob, P1, P1, F(43),F(44), NF,NF, 256);

  // ---- decoder FFN + fused ln3 + logits ----
  k_gemm<1,0><<<gG, blk, 0, stream>>>(P1, Wa+o_w[14], F(46), H0, NB,NF,NF,NF,NF, 256);
  k_gemm<0,5><<<gG, blk, 0, stream>>>(H0, Wa+o_w[15], F(48), logits, P1, F(49),F(50), F(51),F(52), 256);

  k_final<<<dim3(Bb), blk, 0, stream>>>(logits, valid, out);
  #undef F
}

// Round 6
// 1090.089 us; speedup vs baseline: 4.4901x; 1.1407x over previous
//
#include <hip/hip_runtime.h>

// ============================================================================
// TransformerChoiceNet forward. Round 6: attention occupancy restructure —
// q split 4-way (grid 8x128x4), K read direct from global/L2 (no 40KB LDS
// stage), LDS 12KB -> ~75% occupancy. GEMMs unchanged from round 5.
// B=128 S=512 D=64 H=256 NH=8 HD=32, M=B*S=65536.
// ============================================================================

#define Bb  128
#define Ss  512
#define Hh  256
#define NHh 8
#define Mm  (Bb*Ss)

typedef unsigned short bf16_t;
typedef __attribute__((ext_vector_type(8))) short short8;
typedef __attribute__((ext_vector_type(4))) float f32x4;

__device__ __forceinline__ float bf2f(bf16_t h){
  union { unsigned int u; float f; } v; v.u = ((unsigned int)h)<<16; return v.f;
}
__device__ __forceinline__ bf16_t f2bf(float f){
  union { float f; unsigned int u; } v; v.f = f;
  unsigned int r = (v.u + 0x7fffu + ((v.u>>16)&1u)) >> 16;   // RNE
  return (bf16_t)r;
}
__device__ __forceinline__ short8 ld_bf8(const bf16_t* p){   // 16B load
  union { uint4 u; short8 s; } v; v.u = *(const uint4*)p; return v.s;
}
__device__ __forceinline__ void gload16(const bf16_t* g, bf16_t* l){
  __builtin_amdgcn_global_load_lds(
      (const __attribute__((address_space(1))) void*)g,
      (__attribute__((address_space(3))) void*)l, 16, 0, 0);
}
__device__ __forceinline__ float gelu_f(float x){
  float u = 0.7978845608028654f*(x + 0.044715f*x*x*x);
  return 0.5f*x*(1.0f + tanhf(u));
}

// ---------------- weight prep: fp32 W[k][n] -> bf16 Wt[n][k] ------------------
struct PrepDesc { const float* s; unsigned off; int K; };
struct Prep18  { PrepDesc d[18]; };

__global__ __launch_bounds__(256) void k_prep(Prep18 p, bf16_t* __restrict__ arena)
{
  PrepDesc dd = p.d[blockIdx.y];
  int i = blockIdx.x*256 + threadIdx.x;
  if (i < dd.K*256){
    int k = i>>8, n = i&255;
    arena[dd.off + n*dd.K + k] = f2bf(dd.s[i]);
  }
}

// ---------------- LN0 (two gains) + valid mask; bf16 out ----------------------
__global__ __launch_bounds__(256) void k_ln0(const float* __restrict__ src,
    const float* __restrict__ gs, const float* __restrict__ bs,
    const float* __restrict__ gt, const float* __restrict__ bt,
    bf16_t* __restrict__ xs, bf16_t* __restrict__ xt, float* __restrict__ valid)
{
  int row  = blockIdx.x*4 + (threadIdx.x>>6);
  int lane = threadIdx.x & 63;
  float x = src[(size_t)row*64 + lane];
  float s = x;
  #pragma unroll
  for (int o=32;o>0;o>>=1) s += __shfl_xor(s,o);
  float mean = s*(1.0f/64.0f);
  float d = x - mean;
  float ss = d*d;
  #pragma unroll
  for (int o=32;o>0;o>>=1) ss += __shfl_xor(ss,o);
  float r = rsqrtf(ss*(1.0f/64.0f) + 1e-5f);
  float xn = d*r;
  xs[(size_t)row*64+lane] = f2bf(xn*gs[lane] + bs[lane]);
  xt[(size_t)row*64+lane] = f2bf(xn*gt[lane] + bt[lane]);
  if (lane==0) valid[row] = (s != 0.0f) ? 1.0f : 0.0f;
}

// ---------------- MFMA GEMM: block 64m x 256n, BK=64, LDS staged --------------
// (unchanged from round 5)
template<int EPI, int OUTM>
__global__ __launch_bounds__(256,3) void k_gemm(const bf16_t* __restrict__ A,
    const bf16_t* __restrict__ Wt, const float* __restrict__ bias,
    void* __restrict__ Cv, const bf16_t* __restrict__ Pres,
    const float* __restrict__ g, const float* __restrict__ bb,
    const float* __restrict__ oW, const float* __restrict__ obp, int K)
{
  __shared__ bf16_t As[8*512];    // 8 KB
  __shared__ bf16_t Bs[32*512];   // 32 KB
  int t = threadIdx.x, w = t>>6, lane = t&63, l15 = lane&15, quad = lane>>4;
  int m0 = blockIdx.x*64;
  f32x4 z = {0.f,0.f,0.f,0.f};
  f32x4 acc[4][4] = {{z,z,z,z},{z,z,z,z},{z,z,z,z},{z,z,z,z}};

  for (int k0=0; k0<K; k0+=64){
    #pragma unroll
    for (int j=0; j<2; j++){
      int id = 2*w + j; int kc32 = id>>2, mt = id&3;
      gload16(A + (size_t)(m0 + mt*16 + l15)*K + k0 + kc32*32 + quad*8,
              &As[id*512]);
    }
    #pragma unroll
    for (int j=0; j<8; j++){
      int id = 8*w + j; int kc32 = id>>4, gnt = id&15;
      gload16(Wt + (size_t)(gnt*16 + l15)*K + k0 + kc32*32 + quad*8,
              &Bs[id*512]);
    }
    __syncthreads();
    #pragma unroll
    for (int kc=0; kc<2; kc++){
      short8 a[4], b[4];
      #pragma unroll
      for (int mt=0; mt<4; mt++) a[mt] = ld_bf8(&As[(kc*4+mt)*512 + lane*8]);
      #pragma unroll
      for (int nt=0; nt<4; nt++) b[nt] = ld_bf8(&Bs[(kc*16 + w*4 + nt)*512 + lane*8]);
      #pragma unroll
      for (int mt=0; mt<4; mt++)
        #pragma unroll
        for (int nt=0; nt<4; nt++)
          acc[mt][nt] = __builtin_amdgcn_mfma_f32_16x16x32_bf16(a[mt], b[nt], acc[mt][nt], 0,0,0);
    }
    __syncthreads();
  }

  float bv[4];
  #pragma unroll
  for (int nt=0; nt<4; nt++) bv[nt] = bias[w*64 + nt*16 + l15];

  if (OUTM==0 || OUTM==2){
    #pragma unroll
    for (int mt=0; mt<4; mt++)
      #pragma unroll
      for (int nt=0; nt<4; nt++)
        #pragma unroll
        for (int r=0; r<4; r++){
          int row = m0 + mt*16 + quad*4 + r;
          int col = w*64 + nt*16 + l15;
          float v = acc[mt][nt][r] + bv[nt];
          if (EPI==1) v = gelu_f(v);
          if (OUTM==0) ((bf16_t*)Cv)[(size_t)row*256 + col] = f2bf(v);
          else         ((bf16_t*)Cv)[((size_t)(row>>9)*256 + col)*512 + (row&511)] = f2bf(v);
        }
  } else {
    float* RedS = (float*)As;          // [64][4]
    float* RedQ = RedS + 256;          // [64][4]
    #pragma unroll
    for (int mt=0; mt<4; mt++)
      #pragma unroll
      for (int r=0; r<4; r++){
        int row = m0 + mt*16 + quad*4 + r;
        const bf16_t* pr = Pres + (size_t)row*256;
        float s = 0.f, q = 0.f;
        #pragma unroll
        for (int nt=0; nt<4; nt++){
          float v = acc[mt][nt][r] + bv[nt] + bf2f(pr[w*64 + nt*16 + l15]);
          s += v; q += v*v;
        }
        s += __shfl_xor(s,1); s += __shfl_xor(s,2);
        s += __shfl_xor(s,4); s += __shfl_xor(s,8);
        q += __shfl_xor(q,1); q += __shfl_xor(q,2);
        q += __shfl_xor(q,4); q += __shfl_xor(q,8);
        if (l15==0){
          int rr = mt*16 + quad*4 + r;
          RedS[rr*4 + w] = s; RedQ[rr*4 + w] = q;
        }
      }
    __syncthreads();

    float gv[4], bbv[4], wv[4];
    #pragma unroll
    for (int nt=0; nt<4; nt++){ gv[nt] = g[w*64+nt*16+l15]; bbv[nt] = bb[w*64+nt*16+l15]; }
    if (OUTM==5)
      #pragma unroll
      for (int nt=0; nt<4; nt++) wv[nt] = oW[w*64+nt*16+l15];

    float s2p[4][4];
    #pragma unroll
    for (int mt=0; mt<4; mt++)
      #pragma unroll
      for (int r=0; r<4; r++){
        int rr = mt*16 + quad*4 + r;
        int row = m0 + rr;
        float S = RedS[rr*4+0]+RedS[rr*4+1]+RedS[rr*4+2]+RedS[rr*4+3];
        float Q = RedQ[rr*4+0]+RedQ[rr*4+1]+RedQ[rr*4+2]+RedQ[rr*4+3];
        float mean = S*(1.0f/256.0f);
        float var  = Q*(1.0f/256.0f) - mean*mean;
        float rstd = rsqrtf(var + 1e-5f);
        const bf16_t* pr = Pres + (size_t)row*256;
        if (OUTM==3){
          bf16_t* po = (bf16_t*)Cv + (size_t)row*256;
          #pragma unroll
          for (int nt=0; nt<4; nt++){
            float v = acc[mt][nt][r] + bv[nt] + bf2f(pr[w*64 + nt*16 + l15]);
            po[w*64 + nt*16 + l15] = f2bf((v-mean)*rstd*gv[nt] + bbv[nt]);
          }
        } else {
          float s2 = 0.f;
          #pragma unroll
          for (int nt=0; nt<4; nt++){
            float v = acc[mt][nt][r] + bv[nt] + bf2f(pr[w*64 + nt*16 + l15]);
            s2 += ((v-mean)*rstd*gv[nt] + bbv[nt]) * wv[nt];
          }
          s2 += __shfl_xor(s2,1); s2 += __shfl_xor(s2,2);
          s2 += __shfl_xor(s2,4); s2 += __shfl_xor(s2,8);
          s2p[mt][r] = s2;
        }
      }
    if (OUTM==5){
      __syncthreads();
      #pragma unroll
      for (int mt=0; mt<4; mt++)
        #pragma unroll
        for (int r=0; r<4; r++)
          if (l15==0) RedS[(mt*16 + quad*4 + r)*4 + w] = s2p[mt][r];
      __syncthreads();
      if (w==0){
        float S = RedS[lane*4+0]+RedS[lane*4+1]+RedS[lane*4+2]+RedS[lane*4+3];
        ((float*)Cv)[m0 + lane] = S + obp[0];
      }
    }
  }
}

// ---------------- MFMA attention: block per (b,h,128q), high occupancy --------
// Q/K/AO bf16 [M,256] head slice; VT bf16 [B][256][512]. K/V read direct from
// global (L2-resident: 64KB slice shared by 4 q-chunk blocks). LDS 12KB.
// AO aliases Qm safely: block preloads its Q rows before any AO write.
__global__ __launch_bounds__(256) void k_attn(const bf16_t* __restrict__ Qm,
    const bf16_t* __restrict__ Km, const bf16_t* __restrict__ VT,
    const float* __restrict__ valid, bf16_t* __restrict__ AO)
{
  __shared__ bf16_t Pbuf[4][2][16][40];
  __shared__ float  Smask[512];
  int t = threadIdx.x, wave = t>>6, lane = t&63, l15 = lane&15, quad = lane>>4;
  int h = blockIdx.x, b = blockIdx.y, qc = blockIdx.z;
  int q0 = qc*128;
  const float scale = 0.17677669529663687f;   // 1/sqrt(32)

  Smask[t]     = (valid[b*Ss + t      ] != 0.f) ? 0.f : -1e10f;
  Smask[t+256] = (valid[b*Ss + t + 256] != 0.f) ? 0.f : -1e10f;
  __syncthreads();

  short8 aQ0 = ld_bf8(Qm + (size_t)(b*Ss + q0 + (wave*2  )*16 + l15)*256 + h*32 + quad*8);
  short8 aQ1 = ld_bf8(Qm + (size_t)(b*Ss + q0 + (wave*2+1)*16 + l15)*256 + h*32 + quad*8);
  const bf16_t* Vb = VT + ((size_t)b*256 + h*32)*512;

  f32x4 z = {0.f,0.f,0.f,0.f};
  f32x4 O0[2] = {z,z}, O1[2] = {z,z};
  float ls0[4] = {0.f,0.f,0.f,0.f}, ls1[4] = {0.f,0.f,0.f,0.f};

  for (int kt2=0; kt2<16; kt2++){
    #pragma unroll
    for (int half=0; half<2; half++){
      int ktile = kt2*2 + half;
      short8 bK = ld_bf8(Km + (size_t)(b*Ss + ktile*16 + l15)*256 + h*32 + quad*8);
      f32x4 s0 = __builtin_amdgcn_mfma_f32_16x16x32_bf16(aQ0, bK, z, 0,0,0);
      f32x4 s1 = __builtin_amdgcn_mfma_f32_16x16x32_bf16(aQ1, bK, z, 0,0,0);
      float mb = Smask[ktile*16 + l15];
      #pragma unroll
      for (int r=0; r<4; r++){
        float p0 = __expf(s0[r]*scale + mb);   // no max-sub: scores O(5); masked->0
        float p1 = __expf(s1[r]*scale + mb);
        ls0[r] += p0; ls1[r] += p1;
        Pbuf[wave][0][quad*4+r][half*16+l15] = f2bf(p0);
        Pbuf[wave][1][quad*4+r][half*16+l15] = f2bf(p1);
      }
    }
    short8 aP0 = ld_bf8(&Pbuf[wave][0][l15][quad*8]);
    short8 aP1 = ld_bf8(&Pbuf[wave][1][l15][quad*8]);
    #pragma unroll
    for (int nt=0; nt<2; nt++){
      short8 bV = ld_bf8(Vb + (size_t)(nt*16+l15)*512 + kt2*32 + quad*8);
      O0[nt] = __builtin_amdgcn_mfma_f32_16x16x32_bf16(aP0, bV, O0[nt], 0,0,0);
      O1[nt] = __builtin_amdgcn_mfma_f32_16x16x32_bf16(aP1, bV, O1[nt], 0,0,0);
    }
  }

  float i0[4], i1[4];
  #pragma unroll
  for (int r=0; r<4; r++){
    float l0 = ls0[r];
    l0 += __shfl_xor(l0,1); l0 += __shfl_xor(l0,2);
    l0 += __shfl_xor(l0,4); l0 += __shfl_xor(l0,8);
    i0[r] = (l0 > 0.f) ? 1.0f/l0 : 0.f;
    float l1 = ls1[r];
    l1 += __shfl_xor(l1,1); l1 += __shfl_xor(l1,2);
    l1 += __shfl_xor(l1,4); l1 += __shfl_xor(l1,8);
    i1[r] = (l1 > 0.f) ? 1.0f/l1 : 0.f;
  }
  size_t r0 = (size_t)(b*Ss + q0 + (wave*2  )*16);
  size_t r1 = (size_t)(b*Ss + q0 + (wave*2+1)*16);
  #pragma unroll
  for (int nt=0; nt<2; nt++)
    #pragma unroll
    for (int r=0; r<4; r++){
      AO[(r0 + quad*4 + r)*256 + h*32 + nt*16 + l15] = f2bf(O0[nt][r]*i0[r]);
      AO[(r1 + quad*4 + r)*256 + h*32 + nt*16 + l15] = f2bf(O1[nt][r]*i1[r]);
    }
}

// ---------------- final: p = exp(logits)*valid, normalize per batch -----------
__global__ __launch_bounds__(256) void k_final(const float* __restrict__ L,
    const float* __restrict__ valid, float* __restrict__ out)
{
  __shared__ float wsum[4];
  int b = blockIdx.x, t = threadIdx.x;
  float e0 = __expf(L[b*Ss + t      ]) * valid[b*Ss + t      ];
  float e1 = __expf(L[b*Ss + 256 + t]) * valid[b*Ss + 256 + t];
  float s = e0 + e1;
  #pragma unroll
  for (int o=32;o>0;o>>=1) s += __shfl_xor(s,o);
  if ((t&63)==0) wsum[t>>6] = s;
  __syncthreads();
  float tot = wsum[0]+wsum[1]+wsum[2]+wsum[3];
  out[b*Ss + t      ] = e0/tot;
  out[b*Ss + 256 + t] = e1/tot;
}

// ============================================================================
extern "C" void kernel_launch(void* const* d_in, const int* in_sizes, int n_in,
                              void* d_out, int out_size, void* d_ws, size_t ws_size,
                              hipStream_t stream)
{
  #define F(i) ((const float*)d_in[(i)])
  bool sig = (in_sizes[33] == 256);   // signature order vs dict order
  const float* d_eqW  = F(sig?35:33); const float* d_eqb  = F(sig?36:34);
  const float* d_ekW  = F(sig?37:35); const float* d_ekb  = F(sig?38:36);
  const float* d_evW  = F(sig?39:37); const float* d_evb  = F(sig?40:38);
  const float* d_eoW  = F(sig?41:39); const float* d_eob  = F(sig?42:40);
  const float* d_ln1g = F(sig?33:41); const float* d_ln1b = F(sig?34:42);

  // ---- workspace (~163 MiB) ----
  char* w = (char*)d_ws;
  bf16_t* P0 = (bf16_t*)w; w += (size_t)Mm*Hh*2;   // 32 MiB residual (enc)
  bf16_t* P1 = (bf16_t*)w; w += (size_t)Mm*Hh*2;   // 32 MiB residual (dec)
  bf16_t* H0 = (bf16_t*)w; w += (size_t)Mm*Hh*2;   // 32 MiB Q / AO / gelu
  bf16_t* H1 = (bf16_t*)w;                          // 32 MiB K / xs alias
  bf16_t* xs = (bf16_t*)w; w += (size_t)Mm*Hh*2;
  bf16_t* H2 = (bf16_t*)w;                          // 32 MiB VT / xt alias
  bf16_t* xt = (bf16_t*)w; w += (size_t)Mm*Hh*2;
  bf16_t* Wa = (bf16_t*)w; w += (size_t)(2*16384 + 16*65536)*2;  // 2.1 MiB
  float*  valid  = (float*)w; w += (size_t)Mm*4;
  float*  logits = (float*)w; w += (size_t)Mm*4;
  float* out = (float*)d_out;

  unsigned o_sem = 0, o_tem = 16384;
  unsigned o_w[16]; for (int i=0;i<16;i++) o_w[i] = 32768 + i*65536u;
  Prep18 pp;
  const float* srcs[18] = { F(5), F(7), F(9), F(11), F(13), F(15), F(19), F(21),
                            F(25), F(27), F(29), F(31), d_eqW, d_ekW, d_evW, d_eoW,
                            F(45), F(47) };
  unsigned offs[18] = { o_sem, o_tem, o_w[0],o_w[1],o_w[2],o_w[3],o_w[4],o_w[5],
                        o_w[6],o_w[7],o_w[8],o_w[9],o_w[10],o_w[11],o_w[12],o_w[13],
                        o_w[14],o_w[15] };
  for (int i=0;i<18;i++){ pp.d[i].s = srcs[i]; pp.d[i].off = offs[i]; pp.d[i].K = (i<2)?64:256; }

  dim3 blk(256);
  dim3 gLN(Mm/4);
  dim3 gG(Mm/64);
  dim3 gA(NHh, Bb, 4);
  dim3 gP(256, 18);
  const float* NF = nullptr; const bf16_t* NB = nullptr;

  k_prep<<<gP, blk, 0, stream>>>(pp, Wa);
  k_ln0<<<gLN, blk, 0, stream>>>(F(0), F(1),F(2), F(3),F(4), xs, xt, valid);

  k_gemm<0,0><<<gG, blk, 0, stream>>>(xs, Wa+o_sem, F(6), P0, NB,NF,NF,NF,NF, 64);
  k_gemm<0,0><<<gG, blk, 0, stream>>>(xt, Wa+o_tem, F(8), P1, NB,NF,NF,NF,NF, 64);

  // ---- encoder ----
  k_gemm<0,0><<<gG, blk, 0, stream>>>(P0, Wa+o_w[0], F(10), H0, NB,NF,NF,NF,NF, 256);
  k_gemm<0,0><<<gG, blk, 0, stream>>>(P0, Wa+o_w[1], F(12), H1, NB,NF,NF,NF,NF, 256);
  k_gemm<0,2><<<gG, blk, 0, stream>>>(P0, Wa+o_w[2], F(14), H2, NB,NF,NF,NF,NF, 256);
  k_attn<<<gA, blk, 0, stream>>>(H0, H1, H2, valid, H0);
  k_gemm<0,3><<<gG, blk, 0, stream>>>(H0, Wa+o_w[3], F(16), P0, P0, F(17),F(18), NF,NF, 256);
  k_gemm<1,0><<<gG, blk, 0, stream>>>(P0, Wa+o_w[4], F(20), H0, NB,NF,NF,NF,NF, 256);
  k_gemm<0,3><<<gG, blk, 0, stream>>>(H0, Wa+o_w[5], F(22), P0, P0, F(23),F(24), NF,NF, 256);

  // ---- decoder self-attention ----
  k_gemm<0,0><<<gG, blk, 0, stream>>>(P1, Wa+o_w[6], F(26), H0, NB,NF,NF,NF,NF, 256);
  k_gemm<0,0><<<gG, blk, 0, stream>>>(P1, Wa+o_w[7], F(28), H1, NB,NF,NF,NF,NF, 256);
  k_gemm<0,2><<<gG, blk, 0, stream>>>(P1, Wa+o_w[8], F(30), H2, NB,NF,NF,NF,NF, 256);
  k_attn<<<gA, blk, 0, stream>>>(H0, H1, H2, valid, H0);
  k_gemm<0,3><<<gG, blk, 0, stream>>>(H0, Wa+o_w[9], F(32), P1, P1, d_ln1g,d_ln1b, NF,NF, 256);

  // ---- decoder cross-attention ----
  k_gemm<0,0><<<gG, blk, 0, stream>>>(P1, Wa+o_w[10], d_eqb, H0, NB,NF,NF,NF,NF, 256);
  k_gemm<0,0><<<gG, blk, 0, stream>>>(P0, Wa+o_w[11], d_ekb, H1, NB,NF,NF,NF,NF, 256);
  k_gemm<0,2><<<gG, blk, 0, stream>>>(P0, Wa+o_w[12], d_evb, H2, NB,NF,NF,NF,NF, 256);
  k_attn<<<gA, blk, 0, stream>>>(H0, H1, H2, valid, H0);
  k_gemm<0,3><<<gG, blk, 0, stream>>>(H0, Wa+o_w[13], d_eob, P1, P1, F(43),F(44), NF,NF, 256);

  // ---- decoder FFN + fused ln3 + logits ----
  k_gemm<1,0><<<gG, blk, 0, stream>>>(P1, Wa+o_w[14], F(46), H0, NB,NF,NF,NF,NF, 256);
  k_gemm<0,5><<<gG, blk, 0, stream>>>(H0, Wa+o_w[15], F(48), logits, P1, F(49),F(50), F(51),F(52), 256);

  k_final<<<dim3(Bb), blk, 0, stream>>>(logits, valid, out);
  #undef F
}

// Round 7
// 1079.919 us; speedup vs baseline: 4.5324x; 1.0094x over previous
//
#include <hip/hip_runtime.h>
#include <hip/hip_bf16.h>

// ============================================================================
// TransformerChoiceNet forward. Round 7: attention VALU diet — transposed
// QK^T (S^T via mfma(aK,aQ)) so P-writes are contiguous b64 with packed
// v_cvt bf16x2, mask read is one b128, lsum reduce is 2 shuffles; exp scale
// folded into exp2. GEMMs unchanged from round 5.
// B=128 S=512 D=64 H=256 NH=8 HD=32, M=B*S=65536.
// ============================================================================

#define Bb  128
#define Ss  512
#define Hh  256
#define NHh 8
#define Mm  (Bb*Ss)

typedef unsigned short bf16_t;
typedef __attribute__((ext_vector_type(8))) short short8;
typedef __attribute__((ext_vector_type(4))) float f32x4;

__device__ __forceinline__ float bf2f(bf16_t h){
  union { unsigned int u; float f; } v; v.u = ((unsigned int)h)<<16; return v.f;
}
__device__ __forceinline__ bf16_t f2bf(float f){
  union { float f; unsigned int u; } v; v.f = f;
  unsigned int r = (v.u + 0x7fffu + ((v.u>>16)&1u)) >> 16;   // RNE
  return (bf16_t)r;
}
__device__ __forceinline__ unsigned pk_bf16(float a, float b){  // packed RNE cvt
  union { __hip_bfloat162 h; unsigned u; } v;
  v.h = __float22bfloat162_rn(float2{a,b});
  return v.u;
}
__device__ __forceinline__ short8 ld_bf8(const bf16_t* p){   // 16B load
  union { uint4 u; short8 s; } v; v.u = *(const uint4*)p; return v.s;
}
__device__ __forceinline__ void gload16(const bf16_t* g, bf16_t* l){
  __builtin_amdgcn_global_load_lds(
      (const __attribute__((address_space(1))) void*)g,
      (__attribute__((address_space(3))) void*)l, 16, 0, 0);
}
__device__ __forceinline__ float gelu_f(float x){
  float u = 0.7978845608028654f*(x + 0.044715f*x*x*x);
  return 0.5f*x*(1.0f + tanhf(u));
}

// ---------------- weight prep: fp32 W[k][n] -> bf16 Wt[n][k] ------------------
struct PrepDesc { const float* s; unsigned off; int K; };
struct Prep18  { PrepDesc d[18]; };

__global__ __launch_bounds__(256) void k_prep(Prep18 p, bf16_t* __restrict__ arena)
{
  PrepDesc dd = p.d[blockIdx.y];
  int i = blockIdx.x*256 + threadIdx.x;
  if (i < dd.K*256){
    int k = i>>8, n = i&255;
    arena[dd.off + n*dd.K + k] = f2bf(dd.s[i]);
  }
}

// ---------------- LN0 (two gains) + valid mask; bf16 out ----------------------
__global__ __launch_bounds__(256) void k_ln0(const float* __restrict__ src,
    const float* __restrict__ gs, const float* __restrict__ bs,
    const float* __restrict__ gt, const float* __restrict__ bt,
    bf16_t* __restrict__ xs, bf16_t* __restrict__ xt, float* __restrict__ valid)
{
  int row  = blockIdx.x*4 + (threadIdx.x>>6);
  int lane = threadIdx.x & 63;
  float x = src[(size_t)row*64 + lane];
  float s = x;
  #pragma unroll
  for (int o=32;o>0;o>>=1) s += __shfl_xor(s,o);
  float mean = s*(1.0f/64.0f);
  float d = x - mean;
  float ss = d*d;
  #pragma unroll
  for (int o=32;o>0;o>>=1) ss += __shfl_xor(ss,o);
  float r = rsqrtf(ss*(1.0f/64.0f) + 1e-5f);
  float xn = d*r;
  xs[(size_t)row*64+lane] = f2bf(xn*gs[lane] + bs[lane]);
  xt[(size_t)row*64+lane] = f2bf(xn*gt[lane] + bt[lane]);
  if (lane==0) valid[row] = (s != 0.0f) ? 1.0f : 0.0f;
}

// ---------------- MFMA GEMM: block 64m x 256n, BK=64, LDS staged --------------
// (unchanged from round 5)
template<int EPI, int OUTM>
__global__ __launch_bounds__(256,3) void k_gemm(const bf16_t* __restrict__ A,
    const bf16_t* __restrict__ Wt, const float* __restrict__ bias,
    void* __restrict__ Cv, const bf16_t* __restrict__ Pres,
    const float* __restrict__ g, const float* __restrict__ bb,
    const float* __restrict__ oW, const float* __restrict__ obp, int K)
{
  __shared__ bf16_t As[8*512];    // 8 KB
  __shared__ bf16_t Bs[32*512];   // 32 KB
  int t = threadIdx.x, w = t>>6, lane = t&63, l15 = lane&15, quad = lane>>4;
  int m0 = blockIdx.x*64;
  f32x4 z = {0.f,0.f,0.f,0.f};
  f32x4 acc[4][4] = {{z,z,z,z},{z,z,z,z},{z,z,z,z},{z,z,z,z}};

  for (int k0=0; k0<K; k0+=64){
    #pragma unroll
    for (int j=0; j<2; j++){
      int id = 2*w + j; int kc32 = id>>2, mt = id&3;
      gload16(A + (size_t)(m0 + mt*16 + l15)*K + k0 + kc32*32 + quad*8,
              &As[id*512]);
    }
    #pragma unroll
    for (int j=0; j<8; j++){
      int id = 8*w + j; int kc32 = id>>4, gnt = id&15;
      gload16(Wt + (size_t)(gnt*16 + l15)*K + k0 + kc32*32 + quad*8,
              &Bs[id*512]);
    }
    __syncthreads();
    #pragma unroll
    for (int kc=0; kc<2; kc++){
      short8 a[4], b[4];
      #pragma unroll
      for (int mt=0; mt<4; mt++) a[mt] = ld_bf8(&As[(kc*4+mt)*512 + lane*8]);
      #pragma unroll
      for (int nt=0; nt<4; nt++) b[nt] = ld_bf8(&Bs[(kc*16 + w*4 + nt)*512 + lane*8]);
      #pragma unroll
      for (int mt=0; mt<4; mt++)
        #pragma unroll
        for (int nt=0; nt<4; nt++)
          acc[mt][nt] = __builtin_amdgcn_mfma_f32_16x16x32_bf16(a[mt], b[nt], acc[mt][nt], 0,0,0);
    }
    __syncthreads();
  }

  float bv[4];
  #pragma unroll
  for (int nt=0; nt<4; nt++) bv[nt] = bias[w*64 + nt*16 + l15];

  if (OUTM==0 || OUTM==2){
    #pragma unroll
    for (int mt=0; mt<4; mt++)
      #pragma unroll
      for (int nt=0; nt<4; nt++)
        #pragma unroll
        for (int r=0; r<4; r++){
          int row = m0 + mt*16 + quad*4 + r;
          int col = w*64 + nt*16 + l15;
          float v = acc[mt][nt][r] + bv[nt];
          if (EPI==1) v = gelu_f(v);
          if (OUTM==0) ((bf16_t*)Cv)[(size_t)row*256 + col] = f2bf(v);
          else         ((bf16_t*)Cv)[((size_t)(row>>9)*256 + col)*512 + (row&511)] = f2bf(v);
        }
  } else {
    float* RedS = (float*)As;          // [64][4]
    float* RedQ = RedS + 256;          // [64][4]
    #pragma unroll
    for (int mt=0; mt<4; mt++)
      #pragma unroll
      for (int r=0; r<4; r++){
        int row = m0 + mt*16 + quad*4 + r;
        const bf16_t* pr = Pres + (size_t)row*256;
        float s = 0.f, q = 0.f;
        #pragma unroll
        for (int nt=0; nt<4; nt++){
          float v = acc[mt][nt][r] + bv[nt] + bf2f(pr[w*64 + nt*16 + l15]);
          s += v; q += v*v;
        }
        s += __shfl_xor(s,1); s += __shfl_xor(s,2);
        s += __shfl_xor(s,4); s += __shfl_xor(s,8);
        q += __shfl_xor(q,1); q += __shfl_xor(q,2);
        q += __shfl_xor(q,4); q += __shfl_xor(q,8);
        if (l15==0){
          int rr = mt*16 + quad*4 + r;
          RedS[rr*4 + w] = s; RedQ[rr*4 + w] = q;
        }
      }
    __syncthreads();

    float gv[4], bbv[4], wv[4];
    #pragma unroll
    for (int nt=0; nt<4; nt++){ gv[nt] = g[w*64+nt*16+l15]; bbv[nt] = bb[w*64+nt*16+l15]; }
    if (OUTM==5)
      #pragma unroll
      for (int nt=0; nt<4; nt++) wv[nt] = oW[w*64+nt*16+l15];

    float s2p[4][4];
    #pragma unroll
    for (int mt=0; mt<4; mt++)
      #pragma unroll
      for (int r=0; r<4; r++){
        int rr = mt*16 + quad*4 + r;
        int row = m0 + rr;
        float S = RedS[rr*4+0]+RedS[rr*4+1]+RedS[rr*4+2]+RedS[rr*4+3];
        float Q = RedQ[rr*4+0]+RedQ[rr*4+1]+RedQ[rr*4+2]+RedQ[rr*4+3];
        float mean = S*(1.0f/256.0f);
        float var  = Q*(1.0f/256.0f) - mean*mean;
        float rstd = rsqrtf(var + 1e-5f);
        const bf16_t* pr = Pres + (size_t)row*256;
        if (OUTM==3){
          bf16_t* po = (bf16_t*)Cv + (size_t)row*256;
          #pragma unroll
          for (int nt=0; nt<4; nt++){
            float v = acc[mt][nt][r] + bv[nt] + bf2f(pr[w*64 + nt*16 + l15]);
            po[w*64 + nt*16 + l15] = f2bf((v-mean)*rstd*gv[nt] + bbv[nt]);
          }
        } else {
          float s2 = 0.f;
          #pragma unroll
          for (int nt=0; nt<4; nt++){
            float v = acc[mt][nt][r] + bv[nt] + bf2f(pr[w*64 + nt*16 + l15]);
            s2 += ((v-mean)*rstd*gv[nt] + bbv[nt]) * wv[nt];
          }
          s2 += __shfl_xor(s2,1); s2 += __shfl_xor(s2,2);
          s2 += __shfl_xor(s2,4); s2 += __shfl_xor(s2,8);
          s2p[mt][r] = s2;
        }
      }
    if (OUTM==5){
      __syncthreads();
      #pragma unroll
      for (int mt=0; mt<4; mt++)
        #pragma unroll
        for (int r=0; r<4; r++)
          if (l15==0) RedS[(mt*16 + quad*4 + r)*4 + w] = s2p[mt][r];
      __syncthreads();
      if (w==0){
        float S = RedS[lane*4+0]+RedS[lane*4+1]+RedS[lane*4+2]+RedS[lane*4+3];
        ((float*)Cv)[m0 + lane] = S + obp[0];
      }
    }
  }
}

// ---------------- MFMA attention: transposed QK^T, lean VALU ------------------
// Block (h, b, qc): 128 q-rows; wave = 2 q-tiles. S^T = mfma(aK, aQ):
// lane holds S[q=l15][key=ktile*16+quad*4+r] -> contiguous packed P writes,
// float4 mask read, per-lane lsum (reduce = xor16,xor32).
// K/V direct from global (L2-resident). AO aliases Qm safely (preload).
__global__ __launch_bounds__(256) void k_attn(const bf16_t* __restrict__ Qm,
    const bf16_t* __restrict__ Km, const bf16_t* __restrict__ VT,
    const float* __restrict__ valid, bf16_t* __restrict__ AO)
{
  __shared__ bf16_t Pbuf[4][2][16][40];
  __shared__ float  Smask[512];       // 0 or -1e10*log2e (pre-scaled for exp2)
  int t = threadIdx.x, wave = t>>6, lane = t&63, l15 = lane&15, quad = lane>>4;
  int h = blockIdx.x, b = blockIdx.y, qc = blockIdx.z;
  int q0 = qc*128;
  const float kLog2e = 1.4426950408889634f;
  const float scale2 = 0.17677669529663687f * kLog2e;   // (1/sqrt(32))*log2e

  Smask[t]     = (valid[b*Ss + t      ] != 0.f) ? 0.f : -1.0e10f*kLog2e;
  Smask[t+256] = (valid[b*Ss + t + 256] != 0.f) ? 0.f : -1.0e10f*kLog2e;
  __syncthreads();

  short8 aQ0 = ld_bf8(Qm + (size_t)(b*Ss + q0 + (wave*2  )*16 + l15)*256 + h*32 + quad*8);
  short8 aQ1 = ld_bf8(Qm + (size_t)(b*Ss + q0 + (wave*2+1)*16 + l15)*256 + h*32 + quad*8);
  const bf16_t* Vb = VT + ((size_t)b*256 + h*32)*512;

  f32x4 z = {0.f,0.f,0.f,0.f};
  f32x4 O0[2] = {z,z}, O1[2] = {z,z};
  float ls0 = 0.f, ls1 = 0.f;    // per-lane partial rowsum for q=l15

  for (int kt2=0; kt2<16; kt2++){
    #pragma unroll
    for (int half=0; half<2; half++){
      int ktile = kt2*2 + half;
      short8 aK = ld_bf8(Km + (size_t)(b*Ss + ktile*16 + l15)*256 + h*32 + quad*8);
      // S^T tile: lane -> S[q=l15][key=ktile*16+quad*4+r]
      f32x4 s0 = __builtin_amdgcn_mfma_f32_16x16x32_bf16(aK, aQ0, z, 0,0,0);
      f32x4 s1 = __builtin_amdgcn_mfma_f32_16x16x32_bf16(aK, aQ1, z, 0,0,0);
      float4 mb = *(const float4*)&Smask[ktile*16 + quad*4];
      float p00 = exp2f(s0[0]*scale2 + mb.x);
      float p01 = exp2f(s0[1]*scale2 + mb.y);
      float p02 = exp2f(s0[2]*scale2 + mb.z);
      float p03 = exp2f(s0[3]*scale2 + mb.w);
      float p10 = exp2f(s1[0]*scale2 + mb.x);
      float p11 = exp2f(s1[1]*scale2 + mb.y);
      float p12 = exp2f(s1[2]*scale2 + mb.z);
      float p13 = exp2f(s1[3]*scale2 + mb.w);
      ls0 += (p00+p01)+(p02+p03);
      ls1 += (p10+p11)+(p12+p13);
      uint2 w0 = { pk_bf16(p00,p01), pk_bf16(p02,p03) };
      uint2 w1 = { pk_bf16(p10,p11), pk_bf16(p12,p13) };
      *(uint2*)&Pbuf[wave][0][l15][half*16 + quad*4] = w0;
      *(uint2*)&Pbuf[wave][1][l15][half*16 + quad*4] = w1;
    }
    short8 aP0 = ld_bf8(&Pbuf[wave][0][l15][quad*8]);   // A[m=q][k=key], contiguous
    short8 aP1 = ld_bf8(&Pbuf[wave][1][l15][quad*8]);
    #pragma unroll
    for (int nt=0; nt<2; nt++){
      short8 bV = ld_bf8(Vb + (size_t)(nt*16+l15)*512 + kt2*32 + quad*8);
      O0[nt] = __builtin_amdgcn_mfma_f32_16x16x32_bf16(aP0, bV, O0[nt], 0,0,0);
      O1[nt] = __builtin_amdgcn_mfma_f32_16x16x32_bf16(aP1, bV, O1[nt], 0,0,0);
    }
  }

  // rowsum reduce across quads (lanes 16 apart share q=l15)
  ls0 += __shfl_xor(ls0,16); ls0 += __shfl_xor(ls0,32);
  ls1 += __shfl_xor(ls1,16); ls1 += __shfl_xor(ls1,32);
  float linv0 = (ls0 > 0.f) ? 1.0f/ls0 : 0.f;
  float linv1 = (ls1 > 0.f) ? 1.0f/ls1 : 0.f;
  float i0[4], i1[4];
  #pragma unroll
  for (int r=0; r<4; r++){
    i0[r] = __shfl(linv0, quad*4 + r);   // lane quad*4+r has l15 == output row
    i1[r] = __shfl(linv1, quad*4 + r);
  }
  size_t r0 = (size_t)(b*Ss + q0 + (wave*2  )*16);
  size_t r1 = (size_t)(b*Ss + q0 + (wave*2+1)*16);
  #pragma unroll
  for (int nt=0; nt<2; nt++)
    #pragma unroll
    for (int r=0; r<4; r++){
      AO[(r0 + quad*4 + r)*256 + h*32 + nt*16 + l15] = f2bf(O0[nt][r]*i0[r]);
      AO[(r1 + quad*4 + r)*256 + h*32 + nt*16 + l15] = f2bf(O1[nt][r]*i1[r]);
    }
}

// ---------------- final: p = exp(logits)*valid, normalize per batch -----------
__global__ __launch_bounds__(256) void k_final(const float* __restrict__ L,
    const float* __restrict__ valid, float* __restrict__ out)
{
  __shared__ float wsum[4];
  int b = blockIdx.x, t = threadIdx.x;
  float e0 = __expf(L[b*Ss + t      ]) * valid[b*Ss + t      ];
  float e1 = __expf(L[b*Ss + 256 + t]) * valid[b*Ss + 256 + t];
  float s = e0 + e1;
  #pragma unroll
  for (int o=32;o>0;o>>=1) s += __shfl_xor(s,o);
  if ((t&63)==0) wsum[t>>6] = s;
  __syncthreads();
  float tot = wsum[0]+wsum[1]+wsum[2]+wsum[3];
  out[b*Ss + t      ] = e0/tot;
  out[b*Ss + 256 + t] = e1/tot;
}

// ============================================================================
extern "C" void kernel_launch(void* const* d_in, const int* in_sizes, int n_in,
                              void* d_out, int out_size, void* d_ws, size_t ws_size,
                              hipStream_t stream)
{
  #define F(i) ((const float*)d_in[(i)])
  bool sig = (in_sizes[33] == 256);   // signature order vs dict order
  const float* d_eqW  = F(sig?35:33); const float* d_eqb  = F(sig?36:34);
  const float* d_ekW  = F(sig?37:35); const float* d_ekb  = F(sig?38:36);
  const float* d_evW  = F(sig?39:37); const float* d_evb  = F(sig?40:38);
  const float* d_eoW  = F(sig?41:39); const float* d_eob  = F(sig?42:40);
  const float* d_ln1g = F(sig?33:41); const float* d_ln1b = F(sig?34:42);

  // ---- workspace (~163 MiB) ----
  char* w = (char*)d_ws;
  bf16_t* P0 = (bf16_t*)w; w += (size_t)Mm*Hh*2;   // 32 MiB residual (enc)
  bf16_t* P1 = (bf16_t*)w; w += (size_t)Mm*Hh*2;   // 32 MiB residual (dec)
  bf16_t* H0 = (bf16_t*)w; w += (size_t)Mm*Hh*2;   // 32 MiB Q / AO / gelu
  bf16_t* H1 = (bf16_t*)w;                          // 32 MiB K / xs alias
  bf16_t* xs = (bf16_t*)w; w += (size_t)Mm*Hh*2;
  bf16_t* H2 = (bf16_t*)w;                          // 32 MiB VT / xt alias
  bf16_t* xt = (bf16_t*)w; w += (size_t)Mm*Hh*2;
  bf16_t* Wa = (bf16_t*)w; w += (size_t)(2*16384 + 16*65536)*2;  // 2.1 MiB
  float*  valid  = (float*)w; w += (size_t)Mm*4;
  float*  logits = (float*)w; w += (size_t)Mm*4;
  float* out = (float*)d_out;

  unsigned o_sem = 0, o_tem = 16384;
  unsigned o_w[16]; for (int i=0;i<16;i++) o_w[i] = 32768 + i*65536u;
  Prep18 pp;
  const float* srcs[18] = { F(5), F(7), F(9), F(11), F(13), F(15), F(19), F(21),
                            F(25), F(27), F(29), F(31), d_eqW, d_ekW, d_evW, d_eoW,
                            F(45), F(47) };
  unsigned offs[18] = { o_sem, o_tem, o_w[0],o_w[1],o_w[2],o_w[3],o_w[4],o_w[5],
                        o_w[6],o_w[7],o_w[8],o_w[9],o_w[10],o_w[11],o_w[12],o_w[13],
                        o_w[14],o_w[15] };
  for (int i=0;i<18;i++){ pp.d[i].s = srcs[i]; pp.d[i].off = offs[i]; pp.d[i].K = (i<2)?64:256; }

  dim3 blk(256);
  dim3 gLN(Mm/4);
  dim3 gG(Mm/64);
  dim3 gA(NHh, Bb, 4);
  dim3 gP(256, 18);
  const float* NF = nullptr; const bf16_t* NB = nullptr;

  k_prep<<<gP, blk, 0, stream>>>(pp, Wa);
  k_ln0<<<gLN, blk, 0, stream>>>(F(0), F(1),F(2), F(3),F(4), xs, xt, valid);

  k_gemm<0,0><<<gG, blk, 0, stream>>>(xs, Wa+o_sem, F(6), P0, NB,NF,NF,NF,NF, 64);
  k_gemm<0,0><<<gG, blk, 0, stream>>>(xt, Wa+o_tem, F(8), P1, NB,NF,NF,NF,NF, 64);

  // ---- encoder ----
  k_gemm<0,0><<<gG, blk, 0, stream>>>(P0, Wa+o_w[0], F(10), H0, NB,NF,NF,NF,NF, 256);
  k_gemm<0,0><<<gG, blk, 0, stream>>>(P0, Wa+o_w[1], F(12), H1, NB,NF,NF,NF,NF, 256);
  k_gemm<0,2><<<gG, blk, 0, stream>>>(P0, Wa+o_w[2], F(14), H2, NB,NF,NF,NF,NF, 256);
  k_attn<<<gA, blk, 0, stream>>>(H0, H1, H2, valid, H0);
  k_gemm<0,3><<<gG, blk, 0, stream>>>(H0, Wa+o_w[3], F(16), P0, P0, F(17),F(18), NF,NF, 256);
  k_gemm<1,0><<<gG, blk, 0, stream>>>(P0, Wa+o_w[4], F(20), H0, NB,NF,NF,NF,NF, 256);
  k_gemm<0,3><<<gG, blk, 0, stream>>>(H0, Wa+o_w[5], F(22), P0, P0, F(23),F(24), NF,NF, 256);

  // ---- decoder self-attention ----
  k_gemm<0,0><<<gG, blk, 0, stream>>>(P1, Wa+o_w[6], F(26), H0, NB,NF,NF,NF,NF, 256);
  k_gemm<0,0><<<gG, blk, 0, stream>>>(P1, Wa+o_w[7], F(28), H1, NB,NF,NF,NF,NF, 256);
  k_gemm<0,2><<<gG, blk, 0, stream>>>(P1, Wa+o_w[8], F(30), H2, NB,NF,NF,NF,NF, 256);
  k_attn<<<gA, blk, 0, stream>>>(H0, H1, H2, valid, H0);
  k_gemm<0,3><<<gG, blk, 0, stream>>>(H0, Wa+o_w[9], F(32), P1, P1, d_ln1g,d_ln1b, NF,NF, 256);

  // ---- decoder cross-attention ----
  k_gemm<0,0><<<gG, blk, 0, stream>>>(P1, Wa+o_w[10], d_eqb, H0, NB,NF,NF,NF,NF, 256);
  k_gemm<0,0><<<gG, blk, 0, stream>>>(P0, Wa+o_w[11], d_ekb, H1, NB,NF,NF,NF,NF, 256);
  k_gemm<0,2><<<gG, blk, 0, stream>>>(P0, Wa+o_w[12], d_evb, H2, NB,NF,NF,NF,NF, 256);
  k_attn<<<gA, blk, 0, stream>>>(H0, H1, H2, valid, H0);
  k_gemm<0,3><<<gG, blk, 0, stream>>>(H0, Wa+o_w[13], d_eob, P1, P1, F(43),F(44), NF,NF, 256);

  // ---- decoder FFN + fused ln3 + logits ----
  k_gemm<1,0><<<gG, blk, 0, stream>>>(P1, Wa+o_w[14], F(46), H0, NB,NF,NF,NF,NF, 256);
  k_gemm<0,5><<<gG, blk, 0, stream>>>(H0, Wa+o_w[15], F(48), logits, P1, F(49),F(50), F(51),F(52), 256);

  k_final<<<dim3(Bb), blk, 0, stream>>>(logits, valid, out);
  #undef F
}